// Round 4
// baseline (1142.949 us; speedup 1.0000x reference)
//
#include <hip/hip_runtime.h>
#include <hip/hip_bf16.h>

#define NNODES 50000
#define NEDGES 600000

__device__ __forceinline__ float us2f(unsigned short u) {
    unsigned int x = ((unsigned int)u) << 16;
    float f;
    __builtin_memcpy(&f, &x, 4);
    return f;
}
__device__ __forceinline__ unsigned short f2us(float f) {
    unsigned int x;
    __builtin_memcpy(&x, &f, 4);
    unsigned int r = x + 0x7fffu + ((x >> 16) & 1u);  // RNE
    return (unsigned short)(r >> 16);
}

// zero scratch (no hipMemsetAsync anywhere)
__global__ void k_zero(int* deg, int* indeg, float* psum) {
    int i = blockIdx.x * blockDim.x + threadIdx.x;
    if (i < NNODES) { deg[i] = 0; indeg[i] = 0; }
    if (i < 128 * 384) psum[i] = 0.f;
}

// int64-vs-int32 storage detection on edge_index (LE int64 => odd words 0)
__global__ void k_detect_int(const int* ei, int* iflag) {
    if (threadIdx.x == 0 && blockIdx.x == 0) {
        int f = 1;
        for (int i = 1; i < 256; i += 2)
            if (ei[i] != 0) f = 0;
        *iflag = f;
    }
}

// fp32-vs-bf16 storage detection on feature: for packed bf16 pairs, word bits
// 14..7 are the LOW element's exponent byte (clustered ~118..129 for N(0,1));
// for genuine fp32 they are uniform mantissa bits.
__global__ void k_detect_float(const unsigned int* fw, int* fflag) {
    if (threadIdx.x == 0 && blockIdx.x == 0) {
        int hits = 0;
        for (int i = 0; i < 128; ++i) {
            unsigned int e = (fw[i] >> 7) & 0xffu;
            if (e > 100u && e < 160u) hits++;
        }
        *fflag = (hits > 80) ? 1 : 0;  // 1 = bf16 storage, 0 = fp32 storage
    }
}

__global__ void k_batch(const int* pb, const int* iflag, int* b32) {
    int i = blockIdx.x * blockDim.x + threadIdx.x;
    if (i >= NNODES) return;
    int f = *iflag;
    b32[i] = pb[((size_t)i) << f];
}

__global__ void k_degree(const int* ei, const int* iflag, int* deg, int* indeg) {
    int e = blockIdx.x * blockDim.x + threadIdx.x;
    if (e >= NEDGES) return;
    int f = *iflag;
    int s = ei[((size_t)e) << f];
    int d = ei[((size_t)(NEDGES + e)) << f];
    atomicAdd(&deg[s], 1);
    atomicAdd(&indeg[d], 1);
}

__global__ void k_dinv(const int* deg, float* dinv) {
    int i = blockIdx.x * blockDim.x + threadIdx.x;
    if (i >= NNODES) return;
    int d = deg[i];
    dinv[i] = d > 0 ? rsqrtf((float)d) : 0.f;
}

__global__ void k_scan(const int* indeg, int* rowptr, int* cursor) {
    __shared__ int sh[256];
    const int CH = (NNODES + 255) / 256;
    int tid = threadIdx.x;
    int base = tid * CH;
    int s = 0;
    for (int i = 0; i < CH; ++i) {
        int idx = base + i;
        if (idx < NNODES) s += indeg[idx];
    }
    sh[tid] = s;
    __syncthreads();
    for (int off = 1; off < 256; off <<= 1) {
        int t = (tid >= off) ? sh[tid - off] : 0;
        __syncthreads();
        sh[tid] += t;
        __syncthreads();
    }
    int run = sh[tid] - s;
    for (int i = 0; i < CH; ++i) {
        int idx = base + i;
        if (idx < NNODES) {
            rowptr[idx] = run;
            cursor[idx] = run;
            run += indeg[idx];
        }
    }
    if (tid == 255) rowptr[NNODES] = run;
}

__global__ void k_fill(const int* ei, const int* iflag, const float* dinv,
                       int* cursor, int* csr_src, float* csr_w) {
    int e = blockIdx.x * blockDim.x + threadIdx.x;
    if (e >= NEDGES) return;
    int f = *iflag;
    int s = ei[((size_t)e) << f];
    int d = ei[((size_t)(NEDGES + e)) << f];
    float w = -dinv[s] * dinv[d];
    int p = atomicAdd(&cursor[d], 1);
    csr_src[p] = s;
    csr_w[p] = w;
}

// canonicalize feature to bf16 shorts regardless of storage dtype
__global__ void k_featb(const void* src, const int* fflag, int n, unsigned short* dst) {
    int i = blockIdx.x * blockDim.x + threadIdx.x;
    if (i >= n) return;
    if (*fflag) dst[i] = ((const unsigned short*)src)[i];
    else dst[i] = f2us(((const float*)src)[i]);
}

// weights/biases to fp32 regardless of storage dtype
__global__ void k_convw(const void* src, const int* fflag, int n, float* dst) {
    int i = blockIdx.x * blockDim.x + threadIdx.x;
    if (i >= n) return;
    if (*fflag) dst[i] = us2f(((const unsigned short*)src)[i]);
    else dst[i] = ((const float*)src)[i];
}

// out[n,:] = ascale * sum_{e into n} w_e * X[src_e,:] + sscale * sub[n,:]   (bf16 storage)
__global__ void k_prop(const unsigned short* X, const int* rowptr, const int* csr_src,
                       const float* csr_w, const unsigned short* sub,
                       float ascale, float sscale, unsigned short* out) {
    int wid = (blockIdx.x * blockDim.x + threadIdx.x) >> 6;
    int lane = threadIdx.x & 63;
    if (wid >= NNODES) return;
    int beg = rowptr[wid], end = rowptr[wid + 1];
    int f = lane * 2;
    float ax = 0.f, ay = 0.f;
    for (int j = beg; j < end; ++j) {
        int s = csr_src[j];
        float w = csr_w[j];
        unsigned int u = *reinterpret_cast<const unsigned int*>(X + (size_t)s * 128 + f);
        ax += w * us2f((unsigned short)(u & 0xffffu));
        ay += w * us2f((unsigned short)(u >> 16));
    }
    float ox = ascale * ax, oy = ascale * ay;
    if (sub != 0) {
        unsigned int u = *reinterpret_cast<const unsigned int*>(sub + (size_t)wid * 128 + f);
        ox += sscale * us2f((unsigned short)(u & 0xffffu));
        oy += sscale * us2f((unsigned short)(u >> 16));
    }
    unsigned int ov = ((unsigned int)f2us(oy) << 16) | (unsigned int)f2us(ox);
    *reinterpret_cast<unsigned int*>(out + (size_t)wid * 128 + f) = ov;
}

// register-tiled VALU GEMM over X = concat(seg0|seg1|seg2) [NNODES][384] (bf16),
// W fp32 [384][nout]. relu(X@W + bias). pool=0: bf16 store; pool=1: per-graph atomics.
__global__ void k_gemm(const unsigned short* seg0, const unsigned short* seg1,
                       const unsigned short* seg2, const float* W, const float* bias,
                       unsigned short* out, const int* batch32, float* psum,
                       int nout, int pool) {
    int tid = threadIdx.x;
    int tx = tid & 31;
    int ty = tid >> 5;
    int row0 = blockIdx.x * 64 + ty * 8;
    int cb = blockIdx.y * 128 + tx * 4;
    const unsigned short* segs[3];
    segs[0] = seg0; segs[1] = seg1; segs[2] = seg2;
    float acc[8][4];
#pragma unroll
    for (int i = 0; i < 8; ++i)
#pragma unroll
        for (int j = 0; j < 4; ++j) acc[i][j] = 0.f;
    int rows[8];
#pragma unroll
    for (int i = 0; i < 8; ++i) {
        int r = row0 + i;
        rows[i] = r < NNODES ? r : (NNODES - 1);
    }
    for (int kk = 0; kk < 192; ++kk) {
        int kg = kk * 2;
        int sg = kg >> 7;
        int c = kg & 127;
        const unsigned short* S = segs[sg];
        unsigned int xu[8];
#pragma unroll
        for (int i = 0; i < 8; ++i)
            xu[i] = *reinterpret_cast<const unsigned int*>(S + (size_t)rows[i] * 128 + c);
        float w0[4], w1[4];
#pragma unroll
        for (int j = 0; j < 4; ++j) {
            w0[j] = W[(size_t)kg * nout + cb + j];
            w1[j] = W[(size_t)(kg + 1) * nout + cb + j];
        }
#pragma unroll
        for (int i = 0; i < 8; ++i) {
            float xlo = us2f((unsigned short)(xu[i] & 0xffffu));
            float xhi = us2f((unsigned short)(xu[i] >> 16));
#pragma unroll
            for (int j = 0; j < 4; ++j) acc[i][j] += xlo * w0[j] + xhi * w1[j];
        }
    }
    if (pool == 0) {
        for (int i = 0; i < 8; ++i) {
            int r = row0 + i;
            if (r >= NNODES) break;
#pragma unroll
            for (int j = 0; j < 4; ++j) {
                float v = acc[i][j] + bias[cb + j];
                v = v > 0.f ? v : 0.f;
                out[(size_t)r * nout + cb + j] = f2us(v);
            }
        }
    } else {
        int curg = -1;
        float run[4];
        run[0] = 0.f; run[1] = 0.f; run[2] = 0.f; run[3] = 0.f;
        for (int i = 0; i < 8; ++i) {
            int r = row0 + i;
            if (r >= NNODES) break;
            int g = batch32[r];
            if (g != curg) {
                if (curg >= 0) {
#pragma unroll
                    for (int j = 0; j < 4; ++j) atomicAdd(&psum[curg * 384 + cb + j], run[j]);
                }
                curg = g;
#pragma unroll
                for (int j = 0; j < 4; ++j) run[j] = 0.f;
            }
#pragma unroll
            for (int j = 0; j < 4; ++j) {
                float v = acc[i][j] + bias[cb + j];
                run[j] += v > 0.f ? v : 0.f;
            }
        }
        if (curg >= 0) {
#pragma unroll
            for (int j = 0; j < 4; ++j) atomicAdd(&psum[curg * 384 + cb + j], run[j]);
        }
    }
}

__global__ void k_poolfeat(const unsigned short* featb, const int* batch32,
                           float* psum, int* pcnt) {
    int g = blockIdx.x, t = threadIdx.x;
    int lo = 0, hi = NNODES;
    while (lo < hi) { int mid = (lo + hi) >> 1; if (batch32[mid] < g) lo = mid + 1; else hi = mid; }
    int start = lo;
    hi = NNODES;
    while (lo < hi) { int mid = (lo + hi) >> 1; if (batch32[mid] <= g) lo = mid + 1; else hi = mid; }
    int end = lo;
    float acc = 0.f;
    for (int n = start; n < end; ++n) acc += us2f(featb[(size_t)n * 128 + t]);
    psum[g * 384 + 256 + t] = acc;
    if (t == 0) pcnt[g] = end - start;
}

__global__ void k_fc1(const float* psum, const int* pcnt, const float* w,
                      const float* b, float* h) {
    int g = blockIdx.x, j = threadIdx.x * 2;
    int c = pcnt[g];
    float inv = 1.f / (float)(c > 0 ? c : 1);
    float a0 = 0.f, a1 = 0.f;
    for (int k = 0; k < 384; ++k) {
        float p = psum[g * 384 + k];
        a0 += p * w[k * 512 + j];
        a1 += p * w[k * 512 + j + 1];
    }
    a0 = a0 * inv + b[j];
    a1 = a1 * inv + b[j + 1];
    h[g * 512 + j] = a0 > 0.f ? a0 : 0.f;
    h[g * 512 + j + 1] = a1 > 0.f ? a1 : 0.f;
}

// final FC2 + store — carries the harness identifier name on purpose.
__global__ void ChebModel_74380243632480_kernel(const float* h, const float* w,
                                                const float* b, const int* fflag,
                                                void* out) {
    int g = blockIdx.x, j = threadIdx.x;
    float acc = 0.f;
    for (int k = 0; k < 512; ++k) acc += h[g * 512 + k] * w[k * 128 + j];
    acc += b[j];
    if (*fflag) ((unsigned short*)out)[g * 128 + j] = f2us(acc);
    else ((float*)out)[g * 128 + j] = acc;
}

extern "C" void kernel_launch(void* const* d_in, const int* in_sizes, int n_in,
                              void* d_out, int out_size, void* d_ws, size_t ws_size,
                              hipStream_t stream) {
    const void* feature = d_in[0];
    const int* edge_index = (const int*)d_in[1];
    const int* batch = (const int*)d_in[2];
    const void* W1 = d_in[3];
    const void* b1 = d_in[4];
    const void* W2 = d_in[5];
    const void* b2 = d_in[6];
    const void* fc1w = d_in[7];
    const void* fc1b = d_in[8];
    const void* fc2w = d_in[9];
    const void* fc2b = d_in[10];

    char* ws = (char*)d_ws;
    size_t off = 0;
    int* iflag = (int*)(ws + off); off += 256;
    int* fflag = (int*)(ws + off); off += 256;
    int* deg = (int*)(ws + off); off += ((size_t)NNODES * 4 + 255) & ~(size_t)255;
    int* indeg = (int*)(ws + off); off += ((size_t)NNODES * 4 + 255) & ~(size_t)255;
    int* cursor = (int*)(ws + off); off += ((size_t)NNODES * 4 + 255) & ~(size_t)255;
    int* rowptr = (int*)(ws + off); off += ((size_t)(NNODES + 1) * 4 + 255) & ~(size_t)255;
    float* dinv = (float*)(ws + off); off += ((size_t)NNODES * 4 + 255) & ~(size_t)255;
    int* batch32 = (int*)(ws + off); off += ((size_t)NNODES * 4 + 255) & ~(size_t)255;
    int* csr_src = (int*)(ws + off); off += ((size_t)NEDGES * 4 + 255) & ~(size_t)255;
    float* csr_w = (float*)(ws + off); off += ((size_t)NEDGES * 4 + 255) & ~(size_t)255;
    unsigned short* featb = (unsigned short*)(ws + off); off += ((size_t)NNODES * 128 * 2 + 255) & ~(size_t)255;
    unsigned short* T1 = (unsigned short*)(ws + off); off += ((size_t)NNODES * 128 * 2 + 255) & ~(size_t)255;
    unsigned short* T2 = (unsigned short*)(ws + off); off += ((size_t)NNODES * 128 * 2 + 255) & ~(size_t)255;
    unsigned short* gx1 = (unsigned short*)(ws + off); off += ((size_t)NNODES * 128 * 2 + 255) & ~(size_t)255;
    float* W1f = (float*)(ws + off); off += ((size_t)49152 * 4 + 255) & ~(size_t)255;
    float* b1f = (float*)(ws + off); off += 1024;
    float* W2f = (float*)(ws + off); off += ((size_t)98304 * 4 + 255) & ~(size_t)255;
    float* b2f = (float*)(ws + off); off += 1024;
    float* fc1wf = (float*)(ws + off); off += ((size_t)196608 * 4 + 255) & ~(size_t)255;
    float* fc1bf = (float*)(ws + off); off += 2048;
    float* fc2wf = (float*)(ws + off); off += ((size_t)65536 * 4 + 255) & ~(size_t)255;
    float* fc2bf = (float*)(ws + off); off += 1024;
    float* psum = (float*)(ws + off); off += ((size_t)128 * 384 * 4 + 255) & ~(size_t)255;
    int* pcnt = (int*)(ws + off); off += 1024;
    float* hbuf = (float*)(ws + off); off += ((size_t)128 * 512 * 4 + 255) & ~(size_t)255;

    k_zero<<<(NNODES + 255) / 256, 256, 0, stream>>>(deg, indeg, psum);
    k_detect_int<<<1, 64, 0, stream>>>(edge_index, iflag);
    k_detect_float<<<1, 64, 0, stream>>>((const unsigned int*)feature, fflag);
    k_batch<<<(NNODES + 255) / 256, 256, 0, stream>>>(batch, iflag, batch32);
    k_degree<<<(NEDGES + 255) / 256, 256, 0, stream>>>(edge_index, iflag, deg, indeg);
    k_dinv<<<(NNODES + 255) / 256, 256, 0, stream>>>(deg, dinv);
    k_scan<<<1, 256, 0, stream>>>(indeg, rowptr, cursor);
    k_fill<<<(NEDGES + 255) / 256, 256, 0, stream>>>(edge_index, iflag, dinv, cursor, csr_src, csr_w);

    k_featb<<<(NNODES * 128 + 255) / 256, 256, 0, stream>>>(feature, fflag, NNODES * 128, featb);
    k_convw<<<(49152 + 255) / 256, 256, 0, stream>>>(W1, fflag, 49152, W1f);
    k_convw<<<1, 256, 0, stream>>>(b1, fflag, 128, b1f);
    k_convw<<<(98304 + 255) / 256, 256, 0, stream>>>(W2, fflag, 98304, W2f);
    k_convw<<<1, 256, 0, stream>>>(b2, fflag, 256, b2f);
    k_convw<<<(196608 + 255) / 256, 256, 0, stream>>>(fc1w, fflag, 196608, fc1wf);
    k_convw<<<2, 256, 0, stream>>>(fc1b, fflag, 512, fc1bf);
    k_convw<<<(65536 + 255) / 256, 256, 0, stream>>>(fc2w, fflag, 65536, fc2wf);
    k_convw<<<1, 256, 0, stream>>>(fc2b, fflag, 128, fc2bf);

    int pb = (NNODES * 64 + 255) / 256;
    // conv1: T1 = prop(featb), T2 = 2*prop(T1) - featb, gx1 = relu([f|T1|T2]@W1 + b1)
    k_prop<<<pb, 256, 0, stream>>>(featb, rowptr, csr_src, csr_w, (const unsigned short*)0, 1.f, 0.f, T1);
    k_prop<<<pb, 256, 0, stream>>>(T1, rowptr, csr_src, csr_w, featb, 2.f, -1.f, T2);
    {
        dim3 g1((NNODES + 63) / 64, 1);
        k_gemm<<<g1, 256, 0, stream>>>(featb, T1, T2, W1f, b1f, gx1, (const int*)0, (float*)0, 128, 0);
    }
    // conv2 with fused pooling epilogue
    k_prop<<<pb, 256, 0, stream>>>(gx1, rowptr, csr_src, csr_w, (const unsigned short*)0, 1.f, 0.f, T1);
    k_prop<<<pb, 256, 0, stream>>>(T1, rowptr, csr_src, csr_w, gx1, 2.f, -1.f, T2);
    {
        dim3 g2((NNODES + 63) / 64, 2);
        k_gemm<<<g2, 256, 0, stream>>>(gx1, T1, T2, W2f, b2f, (unsigned short*)0, batch32, psum, 256, 1);
    }
    k_poolfeat<<<128, 128, 0, stream>>>(featb, batch32, psum, pcnt);
    k_fc1<<<128, 256, 0, stream>>>(psum, pcnt, fc1wf, fc1bf, hbuf);
    ChebModel_74380243632480_kernel<<<128, 128, 0, stream>>>(hbuf, fc2wf, fc2bf, fflag, d_out);
}

// Round 5
// 964.346 us; speedup vs baseline: 1.1852x; 1.1852x over previous
//
#include <hip/hip_runtime.h>
#include <hip/hip_bf16.h>

#define NNODES 50000
#define NEDGES 600000

typedef short vs8 __attribute__((ext_vector_type(8)));
typedef float floatx4 __attribute__((ext_vector_type(4)));

__device__ __forceinline__ float us2f(unsigned short u) {
    unsigned int x = ((unsigned int)u) << 16;
    float f;
    __builtin_memcpy(&f, &x, 4);
    return f;
}
__device__ __forceinline__ unsigned short f2us(float f) {
    unsigned int x;
    __builtin_memcpy(&x, &f, 4);
    unsigned int r = x + 0x7fffu + ((x >> 16) & 1u);  // RNE
    return (unsigned short)(r >> 16);
}

// zero scratch (no hipMemsetAsync anywhere)
__global__ void k_zero(int* deg, int* indeg, float* psum) {
    int i = blockIdx.x * blockDim.x + threadIdx.x;
    if (i < NNODES) { deg[i] = 0; indeg[i] = 0; }
    if (i < 128 * 384) psum[i] = 0.f;
}

// int64-vs-int32 storage detection on edge_index (LE int64 => odd words 0)
__global__ void k_detect_int(const int* ei, int* iflag) {
    if (threadIdx.x == 0 && blockIdx.x == 0) {
        int f = 1;
        for (int i = 1; i < 256; i += 2)
            if (ei[i] != 0) f = 0;
        *iflag = f;
    }
}

// fp32-vs-bf16 storage detection on feature
__global__ void k_detect_float(const unsigned int* fw, int* fflag) {
    if (threadIdx.x == 0 && blockIdx.x == 0) {
        int hits = 0;
        for (int i = 0; i < 128; ++i) {
            unsigned int e = (fw[i] >> 7) & 0xffu;
            if (e > 100u && e < 160u) hits++;
        }
        *fflag = (hits > 80) ? 1 : 0;  // 1 = bf16 storage, 0 = fp32 storage
    }
}

__global__ void k_batch(const int* pb, const int* iflag, int* b32) {
    int i = blockIdx.x * blockDim.x + threadIdx.x;
    if (i >= NNODES) return;
    int f = *iflag;
    b32[i] = pb[((size_t)i) << f];
}

__global__ void k_degree(const int* ei, const int* iflag, int* deg, int* indeg) {
    int e = blockIdx.x * blockDim.x + threadIdx.x;
    if (e >= NEDGES) return;
    int f = *iflag;
    int s = ei[((size_t)e) << f];
    int d = ei[((size_t)(NEDGES + e)) << f];
    atomicAdd(&deg[s], 1);
    atomicAdd(&indeg[d], 1);
}

__global__ void k_dinv(const int* deg, float* dinv) {
    int i = blockIdx.x * blockDim.x + threadIdx.x;
    if (i >= NNODES) return;
    int d = deg[i];
    dinv[i] = d > 0 ? rsqrtf((float)d) : 0.f;
}

__global__ void k_scan(const int* indeg, int* rowptr, int* cursor) {
    __shared__ int sh[256];
    const int CH = (NNODES + 255) / 256;
    int tid = threadIdx.x;
    int base = tid * CH;
    int s = 0;
    for (int i = 0; i < CH; ++i) {
        int idx = base + i;
        if (idx < NNODES) s += indeg[idx];
    }
    sh[tid] = s;
    __syncthreads();
    for (int off = 1; off < 256; off <<= 1) {
        int t = (tid >= off) ? sh[tid - off] : 0;
        __syncthreads();
        sh[tid] += t;
        __syncthreads();
    }
    int run = sh[tid] - s;
    for (int i = 0; i < CH; ++i) {
        int idx = base + i;
        if (idx < NNODES) {
            rowptr[idx] = run;
            cursor[idx] = run;
            run += indeg[idx];
        }
    }
    if (tid == 255) rowptr[NNODES] = run;
}

__global__ void k_fill(const int* ei, const int* iflag, const float* dinv,
                       int* cursor, int* csr_src, float* csr_w) {
    int e = blockIdx.x * blockDim.x + threadIdx.x;
    if (e >= NEDGES) return;
    int f = *iflag;
    int s = ei[((size_t)e) << f];
    int d = ei[((size_t)(NEDGES + e)) << f];
    float w = -dinv[s] * dinv[d];
    int p = atomicAdd(&cursor[d], 1);
    csr_src[p] = s;
    csr_w[p] = w;
}

// canonicalize feature to bf16 shorts regardless of storage dtype
__global__ void k_featb(const void* src, const int* fflag, int n, unsigned short* dst) {
    int i = blockIdx.x * blockDim.x + threadIdx.x;
    if (i >= n) return;
    if (*fflag) dst[i] = ((const unsigned short*)src)[i];
    else dst[i] = f2us(((const float*)src)[i]);
}

// weights/biases to fp32 regardless of storage dtype
__global__ void k_convw(const void* src, const int* fflag, int n, float* dst) {
    int i = blockIdx.x * blockDim.x + threadIdx.x;
    if (i >= n) return;
    if (*fflag) dst[i] = us2f(((const unsigned short*)src)[i]);
    else dst[i] = ((const float*)src)[i];
}

// transpose conv weight [ktot][nout] -> bf16 [nout][ktot]
__global__ void k_trans(const void* src, const int* fflag, int ktot, int nout,
                        unsigned short* dst) {
    int idx = blockIdx.x * blockDim.x + threadIdx.x;
    if (idx >= ktot * nout) return;
    int n = idx / ktot, k = idx - n * ktot;
    if (*fflag) dst[idx] = ((const unsigned short*)src)[k * nout + n];
    else dst[idx] = f2us(((const float*)src)[k * nout + n]);
}

// out[n,:] = ascale * sum_{e into n} w_e * X[src_e,:] + sscale * sub[n,:]   (bf16 storage)
__global__ void k_prop(const unsigned short* X, const int* rowptr, const int* csr_src,
                       const float* csr_w, const unsigned short* sub,
                       float ascale, float sscale, unsigned short* out) {
    int wid = (blockIdx.x * blockDim.x + threadIdx.x) >> 6;
    int lane = threadIdx.x & 63;
    if (wid >= NNODES) return;
    int beg = rowptr[wid], end = rowptr[wid + 1];
    int f = lane * 2;
    float ax = 0.f, ay = 0.f;
    for (int j = beg; j < end; ++j) {
        int s = csr_src[j];
        float w = csr_w[j];
        unsigned int u = *reinterpret_cast<const unsigned int*>(X + (size_t)s * 128 + f);
        ax += w * us2f((unsigned short)(u & 0xffffu));
        ay += w * us2f((unsigned short)(u >> 16));
    }
    float ox = ascale * ax, oy = ascale * ay;
    if (sub != 0) {
        unsigned int u = *reinterpret_cast<const unsigned int*>(sub + (size_t)wid * 128 + f);
        ox += sscale * us2f((unsigned short)(u & 0xffffu));
        oy += sscale * us2f((unsigned short)(u >> 16));
    }
    unsigned int ov = ((unsigned int)f2us(oy) << 16) | (unsigned int)f2us(ox);
    *reinterpret_cast<unsigned int*>(out + (size_t)wid * 128 + f) = ov;
}

// ---- MFMA conv1 GEMM: gx1 = relu([featb|T1|T2] @ W1 + b1), nout=128 ----
// wave per 16 rows; A frag: row=lane&15, k=(lane>>4)*8+j; B from Wt[n][384];
// D: col=lane&15, row=(lane>>4)*4+reg.
__global__ __launch_bounds__(256) void k_conv1_gemm(
    const unsigned short* seg0, const unsigned short* seg1, const unsigned short* seg2,
    const unsigned short* Wt, const float* bias, unsigned short* out) {
    int wv = threadIdx.x >> 6, lane = threadIdx.x & 63;
    int m = lane & 15, kq = lane >> 4;
    int row0 = (blockIdx.x * 4 + wv) * 16;
    int rr = row0 + m;
    if (rr >= NNODES) rr = NNODES - 1;
    floatx4 acc[8];
#pragma unroll
    for (int t = 0; t < 8; ++t) { acc[t][0] = 0.f; acc[t][1] = 0.f; acc[t][2] = 0.f; acc[t][3] = 0.f; }
    const unsigned short* segs[3];
    segs[0] = seg0; segs[1] = seg1; segs[2] = seg2;
#pragma unroll
    for (int sgi = 0; sgi < 3; ++sgi) {
        const unsigned short* S = segs[sgi] + (size_t)rr * 128 + kq * 8;
        const unsigned short* Bp = Wt + sgi * 128 + kq * 8;
#pragma unroll
        for (int k4 = 0; k4 < 4; ++k4) {
            vs8 a = *reinterpret_cast<const vs8*>(S + k4 * 32);
#pragma unroll
            for (int t = 0; t < 8; ++t) {
                vs8 b = *reinterpret_cast<const vs8*>(Bp + (size_t)(t * 16 + m) * 384 + k4 * 32);
                acc[t] = __builtin_amdgcn_mfma_f32_16x16x32_bf16(a, b, acc[t], 0, 0, 0);
            }
        }
    }
    int orow_base = row0 + kq * 4;
#pragma unroll
    for (int t = 0; t < 8; ++t) {
        int col = t * 16 + m;
        float bv = bias[col];
#pragma unroll
        for (int i = 0; i < 4; ++i) {
            int r = orow_base + i;
            if (r < NNODES) {
                float v = acc[t][i] + bv;
                v = v > 0.f ? v : 0.f;
                out[(size_t)r * 128 + col] = f2us(v);
            }
        }
    }
}

// ---- MFMA conv2 GEMM + fused mean-pool epilogue: nout=256, atomics into psum ----
__global__ __launch_bounds__(256) void k_conv2_gemm(
    const unsigned short* seg0, const unsigned short* seg1, const unsigned short* seg2,
    const unsigned short* Wt, const float* bias, const int* batch32, float* psum) {
    int wv = threadIdx.x >> 6, lane = threadIdx.x & 63;
    int m = lane & 15, kq = lane >> 4;
    int row0 = (blockIdx.x * 4 + wv) * 16;
    int rr = row0 + m;
    if (rr >= NNODES) rr = NNODES - 1;
    floatx4 acc[16];
#pragma unroll
    for (int t = 0; t < 16; ++t) { acc[t][0] = 0.f; acc[t][1] = 0.f; acc[t][2] = 0.f; acc[t][3] = 0.f; }
    const unsigned short* segs[3];
    segs[0] = seg0; segs[1] = seg1; segs[2] = seg2;
#pragma unroll
    for (int sgi = 0; sgi < 3; ++sgi) {
        const unsigned short* S = segs[sgi] + (size_t)rr * 128 + kq * 8;
        const unsigned short* Bp = Wt + sgi * 128 + kq * 8;
#pragma unroll
        for (int k4 = 0; k4 < 4; ++k4) {
            vs8 a = *reinterpret_cast<const vs8*>(S + k4 * 32);
#pragma unroll
            for (int t = 0; t < 16; ++t) {
                vs8 b = *reinterpret_cast<const vs8*>(Bp + (size_t)(t * 16 + m) * 384 + k4 * 32);
                acc[t] = __builtin_amdgcn_mfma_f32_16x16x32_bf16(a, b, acc[t], 0, 0, 0);
            }
        }
    }
    int orow_base = row0 + kq * 4;
    int gid[4];
#pragma unroll
    for (int i = 0; i < 4; ++i) {
        int r = orow_base + i;
        gid[i] = r < NNODES ? batch32[r] : -1;
    }
#pragma unroll
    for (int t = 0; t < 16; ++t) {
        int col = t * 16 + m;
        float bv = bias[col];
        float run = 0.f;
        int curg = -1;
#pragma unroll
        for (int i = 0; i < 4; ++i) {
            int g = gid[i];
            if (g < 0) break;
            float v = acc[t][i] + bv;
            v = v > 0.f ? v : 0.f;
            if (g != curg) {
                if (curg >= 0) atomicAdd(&psum[curg * 384 + col], run);
                curg = g;
                run = 0.f;
            }
            run += v;
        }
        if (curg >= 0) atomicAdd(&psum[curg * 384 + col], run);
    }
}

__global__ void k_poolfeat(const unsigned short* featb, const int* batch32,
                           float* psum, int* pcnt) {
    int g = blockIdx.x, t = threadIdx.x;
    int lo = 0, hi = NNODES;
    while (lo < hi) { int mid = (lo + hi) >> 1; if (batch32[mid] < g) lo = mid + 1; else hi = mid; }
    int start = lo;
    hi = NNODES;
    while (lo < hi) { int mid = (lo + hi) >> 1; if (batch32[mid] <= g) lo = mid + 1; else hi = mid; }
    int end = lo;
    float acc = 0.f;
    for (int n = start; n < end; ++n) acc += us2f(featb[(size_t)n * 128 + t]);
    psum[g * 384 + 256 + t] = acc;
    if (t == 0) pcnt[g] = end - start;
}

__global__ void k_fc1(const float* psum, const int* pcnt, const float* w,
                      const float* b, float* h) {
    int g = blockIdx.x, j = threadIdx.x * 2;
    int c = pcnt[g];
    float inv = 1.f / (float)(c > 0 ? c : 1);
    float a0 = 0.f, a1 = 0.f;
    for (int k = 0; k < 384; ++k) {
        float p = psum[g * 384 + k];
        a0 += p * w[k * 512 + j];
        a1 += p * w[k * 512 + j + 1];
    }
    a0 = a0 * inv + b[j];
    a1 = a1 * inv + b[j + 1];
    h[g * 512 + j] = a0 > 0.f ? a0 : 0.f;
    h[g * 512 + j + 1] = a1 > 0.f ? a1 : 0.f;
}

// final FC2 + store — carries the harness identifier name on purpose.
__global__ void ChebModel_74380243632480_kernel(const float* h, const float* w,
                                                const float* b, const int* fflag,
                                                void* out) {
    int g = blockIdx.x, j = threadIdx.x;
    float acc = 0.f;
    for (int k = 0; k < 512; ++k) acc += h[g * 512 + k] * w[k * 128 + j];
    acc += b[j];
    if (*fflag) ((unsigned short*)out)[g * 128 + j] = f2us(acc);
    else ((float*)out)[g * 128 + j] = acc;
}

extern "C" void kernel_launch(void* const* d_in, const int* in_sizes, int n_in,
                              void* d_out, int out_size, void* d_ws, size_t ws_size,
                              hipStream_t stream) {
    const void* feature = d_in[0];
    const int* edge_index = (const int*)d_in[1];
    const int* batch = (const int*)d_in[2];
    const void* W1 = d_in[3];
    const void* b1 = d_in[4];
    const void* W2 = d_in[5];
    const void* b2 = d_in[6];
    const void* fc1w = d_in[7];
    const void* fc1b = d_in[8];
    const void* fc2w = d_in[9];
    const void* fc2b = d_in[10];

    char* ws = (char*)d_ws;
    size_t off = 0;
    int* iflag = (int*)(ws + off); off += 256;
    int* fflag = (int*)(ws + off); off += 256;
    int* deg = (int*)(ws + off); off += ((size_t)NNODES * 4 + 255) & ~(size_t)255;
    int* indeg = (int*)(ws + off); off += ((size_t)NNODES * 4 + 255) & ~(size_t)255;
    int* cursor = (int*)(ws + off); off += ((size_t)NNODES * 4 + 255) & ~(size_t)255;
    int* rowptr = (int*)(ws + off); off += ((size_t)(NNODES + 1) * 4 + 255) & ~(size_t)255;
    float* dinv = (float*)(ws + off); off += ((size_t)NNODES * 4 + 255) & ~(size_t)255;
    int* batch32 = (int*)(ws + off); off += ((size_t)NNODES * 4 + 255) & ~(size_t)255;
    int* csr_src = (int*)(ws + off); off += ((size_t)NEDGES * 4 + 255) & ~(size_t)255;
    float* csr_w = (float*)(ws + off); off += ((size_t)NEDGES * 4 + 255) & ~(size_t)255;
    unsigned short* featb = (unsigned short*)(ws + off); off += ((size_t)NNODES * 128 * 2 + 255) & ~(size_t)255;
    unsigned short* T1 = (unsigned short*)(ws + off); off += ((size_t)NNODES * 128 * 2 + 255) & ~(size_t)255;
    unsigned short* T2 = (unsigned short*)(ws + off); off += ((size_t)NNODES * 128 * 2 + 255) & ~(size_t)255;
    unsigned short* gx1 = (unsigned short*)(ws + off); off += ((size_t)NNODES * 128 * 2 + 255) & ~(size_t)255;
    unsigned short* W1t = (unsigned short*)(ws + off); off += ((size_t)49152 * 2 + 255) & ~(size_t)255;
    unsigned short* W2t = (unsigned short*)(ws + off); off += ((size_t)98304 * 2 + 255) & ~(size_t)255;
    float* b1f = (float*)(ws + off); off += 1024;
    float* b2f = (float*)(ws + off); off += 1024;
    float* fc1wf = (float*)(ws + off); off += ((size_t)196608 * 4 + 255) & ~(size_t)255;
    float* fc1bf = (float*)(ws + off); off += 2048;
    float* fc2wf = (float*)(ws + off); off += ((size_t)65536 * 4 + 255) & ~(size_t)255;
    float* fc2bf = (float*)(ws + off); off += 1024;
    float* psum = (float*)(ws + off); off += ((size_t)128 * 384 * 4 + 255) & ~(size_t)255;
    int* pcnt = (int*)(ws + off); off += 1024;
    float* hbuf = (float*)(ws + off); off += ((size_t)128 * 512 * 4 + 255) & ~(size_t)255;

    k_zero<<<(NNODES + 255) / 256, 256, 0, stream>>>(deg, indeg, psum);
    k_detect_int<<<1, 64, 0, stream>>>(edge_index, iflag);
    k_detect_float<<<1, 64, 0, stream>>>((const unsigned int*)feature, fflag);
    k_batch<<<(NNODES + 255) / 256, 256, 0, stream>>>(batch, iflag, batch32);
    k_degree<<<(NEDGES + 255) / 256, 256, 0, stream>>>(edge_index, iflag, deg, indeg);
    k_dinv<<<(NNODES + 255) / 256, 256, 0, stream>>>(deg, dinv);
    k_scan<<<1, 256, 0, stream>>>(indeg, rowptr, cursor);
    k_fill<<<(NEDGES + 255) / 256, 256, 0, stream>>>(edge_index, iflag, dinv, cursor, csr_src, csr_w);

    k_featb<<<(NNODES * 128 + 255) / 256, 256, 0, stream>>>(feature, fflag, NNODES * 128, featb);
    k_trans<<<(49152 + 255) / 256, 256, 0, stream>>>(W1, fflag, 384, 128, W1t);
    k_trans<<<(98304 + 255) / 256, 256, 0, stream>>>(W2, fflag, 384, 256, W2t);
    k_convw<<<1, 256, 0, stream>>>(b1, fflag, 128, b1f);
    k_convw<<<1, 256, 0, stream>>>(b2, fflag, 256, b2f);
    k_convw<<<(196608 + 255) / 256, 256, 0, stream>>>(fc1w, fflag, 196608, fc1wf);
    k_convw<<<2, 256, 0, stream>>>(fc1b, fflag, 512, fc1bf);
    k_convw<<<(65536 + 255) / 256, 256, 0, stream>>>(fc2w, fflag, 65536, fc2wf);
    k_convw<<<1, 256, 0, stream>>>(fc2b, fflag, 128, fc2bf);

    int pb = (NNODES * 64 + 255) / 256;
    // conv1: T1 = prop(featb), T2 = 2*prop(T1) - featb, gx1 = relu([f|T1|T2]@W1 + b1)
    k_prop<<<pb, 256, 0, stream>>>(featb, rowptr, csr_src, csr_w, (const unsigned short*)0, 1.f, 0.f, T1);
    k_prop<<<pb, 256, 0, stream>>>(T1, rowptr, csr_src, csr_w, featb, 2.f, -1.f, T2);
    k_conv1_gemm<<<(NNODES + 63) / 64, 256, 0, stream>>>(featb, T1, T2, W1t, b1f, gx1);
    // conv2 with fused mean-pool epilogue
    k_prop<<<pb, 256, 0, stream>>>(gx1, rowptr, csr_src, csr_w, (const unsigned short*)0, 1.f, 0.f, T1);
    k_prop<<<pb, 256, 0, stream>>>(T1, rowptr, csr_src, csr_w, gx1, 2.f, -1.f, T2);
    k_conv2_gemm<<<(NNODES + 63) / 64, 256, 0, stream>>>(gx1, T1, T2, W2t, b2f, batch32, psum);
    // feature part of pooling + counts, then FC head
    k_poolfeat<<<128, 128, 0, stream>>>(featb, batch32, psum, pcnt);
    k_fc1<<<128, 256, 0, stream>>>(psum, pcnt, fc1wf, fc1bf, hbuf);
    ChebModel_74380243632480_kernel<<<128, 128, 0, stream>>>(hbuf, fc2wf, fc2bf, fflag, d_out);
}

// Round 6
// 930.322 us; speedup vs baseline: 1.2286x; 1.0366x over previous
//
#include <hip/hip_runtime.h>
#include <hip/hip_bf16.h>

#define NNODES 50000
#define NEDGES 600000

typedef short vs8 __attribute__((ext_vector_type(8)));
typedef float floatx4 __attribute__((ext_vector_type(4)));

__device__ __forceinline__ float us2f(unsigned short u) {
    unsigned int x = ((unsigned int)u) << 16;
    float f;
    __builtin_memcpy(&f, &x, 4);
    return f;
}
__device__ __forceinline__ unsigned short f2us(float f) {
    unsigned int x;
    __builtin_memcpy(&x, &f, 4);
    unsigned int r = x + 0x7fffu + ((x >> 16) & 1u);  // RNE
    return (unsigned short)(r >> 16);
}

// zero scratch (no hipMemsetAsync anywhere)
__global__ void k_zero(int* deg, int* indeg, float* psum) {
    int i = blockIdx.x * blockDim.x + threadIdx.x;
    if (i < NNODES) { deg[i] = 0; indeg[i] = 0; }
    if (i < 128 * 384) psum[i] = 0.f;
}

// int64-vs-int32 storage detection on edge_index (LE int64 => odd words 0)
__global__ void k_detect_int(const int* ei, int* iflag) {
    if (threadIdx.x == 0 && blockIdx.x == 0) {
        int f = 1;
        for (int i = 1; i < 256; i += 2)
            if (ei[i] != 0) f = 0;
        *iflag = f;
    }
}

// fp32-vs-bf16 storage detection on feature
__global__ void k_detect_float(const unsigned int* fw, int* fflag) {
    if (threadIdx.x == 0 && blockIdx.x == 0) {
        int hits = 0;
        for (int i = 0; i < 128; ++i) {
            unsigned int e = (fw[i] >> 7) & 0xffu;
            if (e > 100u && e < 160u) hits++;
        }
        *fflag = (hits > 80) ? 1 : 0;  // 1 = bf16 storage, 0 = fp32 storage
    }
}

__global__ void k_batch(const int* pb, const int* iflag, int* b32) {
    int i = blockIdx.x * blockDim.x + threadIdx.x;
    if (i >= NNODES) return;
    int f = *iflag;
    b32[i] = pb[((size_t)i) << f];
}

__global__ void k_degree(const int* ei, const int* iflag, int* deg, int* indeg) {
    int e = blockIdx.x * blockDim.x + threadIdx.x;
    if (e >= NEDGES) return;
    int f = *iflag;
    int s = ei[((size_t)e) << f];
    int d = ei[((size_t)(NEDGES + e)) << f];
    atomicAdd(&deg[s], 1);
    atomicAdd(&indeg[d], 1);
}

__global__ void k_dinv(const int* deg, float* dinv) {
    int i = blockIdx.x * blockDim.x + threadIdx.x;
    if (i >= NNODES) return;
    int d = deg[i];
    dinv[i] = d > 0 ? rsqrtf((float)d) : 0.f;
}

__global__ void k_scan(const int* indeg, int* rowptr, int* cursor) {
    __shared__ int sh[256];
    const int CH = (NNODES + 255) / 256;
    int tid = threadIdx.x;
    int base = tid * CH;
    int s = 0;
    for (int i = 0; i < CH; ++i) {
        int idx = base + i;
        if (idx < NNODES) s += indeg[idx];
    }
    sh[tid] = s;
    __syncthreads();
    for (int off = 1; off < 256; off <<= 1) {
        int t = (tid >= off) ? sh[tid - off] : 0;
        __syncthreads();
        sh[tid] += t;
        __syncthreads();
    }
    int run = sh[tid] - s;
    for (int i = 0; i < CH; ++i) {
        int idx = base + i;
        if (idx < NNODES) {
            rowptr[idx] = run;
            cursor[idx] = run;
            run += indeg[idx];
        }
    }
    if (tid == 255) rowptr[NNODES] = run;
}

__global__ void k_fill(const int* ei, const int* iflag, const float* dinv,
                       int* cursor, int* csr_src, float* csr_w) {
    int e = blockIdx.x * blockDim.x + threadIdx.x;
    if (e >= NEDGES) return;
    int f = *iflag;
    int s = ei[((size_t)e) << f];
    int d = ei[((size_t)(NEDGES + e)) << f];
    float w = -dinv[s] * dinv[d];
    int p = atomicAdd(&cursor[d], 1);
    csr_src[p] = s;
    csr_w[p] = w;
}

// canonicalize feature to bf16 shorts regardless of storage dtype
__global__ void k_featb(const void* src, const int* fflag, int n, unsigned short* dst) {
    int i = blockIdx.x * blockDim.x + threadIdx.x;
    if (i >= n) return;
    if (*fflag) dst[i] = ((const unsigned short*)src)[i];
    else dst[i] = f2us(((const float*)src)[i]);
}

// weights/biases to fp32 regardless of storage dtype
__global__ void k_convw(const void* src, const int* fflag, int n, float* dst) {
    int i = blockIdx.x * blockDim.x + threadIdx.x;
    if (i >= n) return;
    if (*fflag) dst[i] = us2f(((const unsigned short*)src)[i]);
    else dst[i] = ((const float*)src)[i];
}

// transpose conv weight [ktot][nout] -> bf16 [nout][ktot]
__global__ void k_trans(const void* src, const int* fflag, int ktot, int nout,
                        unsigned short* dst) {
    int idx = blockIdx.x * blockDim.x + threadIdx.x;
    if (idx >= ktot * nout) return;
    int n = idx / ktot, k = idx - n * ktot;
    if (*fflag) dst[idx] = ((const unsigned short*)src)[k * nout + n];
    else dst[idx] = f2us(((const float*)src)[k * nout + n]);
}

// out[n,:] = ascale * sum_{e into n} w_e * X[src_e,:] + sscale * sub[n,:]   (bf16 storage)
__global__ void k_prop(const unsigned short* X, const int* rowptr, const int* csr_src,
                       const float* csr_w, const unsigned short* sub,
                       float ascale, float sscale, unsigned short* out) {
    int wid = (blockIdx.x * blockDim.x + threadIdx.x) >> 6;
    int lane = threadIdx.x & 63;
    if (wid >= NNODES) return;
    int beg = rowptr[wid], end = rowptr[wid + 1];
    int f = lane * 2;
    float ax = 0.f, ay = 0.f;
    for (int j = beg; j < end; ++j) {
        int s = csr_src[j];
        float w = csr_w[j];
        unsigned int u = *reinterpret_cast<const unsigned int*>(X + (size_t)s * 128 + f);
        ax += w * us2f((unsigned short)(u & 0xffffu));
        ay += w * us2f((unsigned short)(u >> 16));
    }
    float ox = ascale * ax, oy = ascale * ay;
    if (sub != 0) {
        unsigned int u = *reinterpret_cast<const unsigned int*>(sub + (size_t)wid * 128 + f);
        ox += sscale * us2f((unsigned short)(u & 0xffffu));
        oy += sscale * us2f((unsigned short)(u >> 16));
    }
    unsigned int ov = ((unsigned int)f2us(oy) << 16) | (unsigned int)f2us(ox);
    *reinterpret_cast<unsigned int*>(out + (size_t)wid * 128 + f) = ov;
}

// ---- MFMA conv1 GEMM: gx1 = relu([featb|T1|T2] @ W1 + b1), nout=128 ----
// wave per 16 rows x 64 cols (4 MFMA tiles); grid.y selects the 64-col slab.
// A frag: row=lane&15, k=(lane>>4)*8+j; B from Wt[n][384]; D: col=lane&15, row=(lane>>4)*4+reg.
__global__ __launch_bounds__(256) void k_conv1_gemm(
    const unsigned short* seg0, const unsigned short* seg1, const unsigned short* seg2,
    const unsigned short* Wt, const float* bias, unsigned short* out) {
    int wv = threadIdx.x >> 6, lane = threadIdx.x & 63;
    int m = lane & 15, kq = lane >> 4;
    int row0 = (blockIdx.x * 4 + wv) * 16;
    int col0 = blockIdx.y * 64;
    int rr = row0 + m;
    if (rr >= NNODES) rr = NNODES - 1;
    floatx4 acc[4];
#pragma unroll
    for (int t = 0; t < 4; ++t) { acc[t][0] = 0.f; acc[t][1] = 0.f; acc[t][2] = 0.f; acc[t][3] = 0.f; }
    const unsigned short* segs[3];
    segs[0] = seg0; segs[1] = seg1; segs[2] = seg2;
#pragma unroll
    for (int sgi = 0; sgi < 3; ++sgi) {
        const unsigned short* S = segs[sgi] + (size_t)rr * 128 + kq * 8;
        const unsigned short* Bp = Wt + (size_t)(col0 + m) * 384 + sgi * 128 + kq * 8;
#pragma unroll
        for (int k4 = 0; k4 < 4; ++k4) {
            vs8 a = *reinterpret_cast<const vs8*>(S + k4 * 32);
#pragma unroll
            for (int t = 0; t < 4; ++t) {
                vs8 b = *reinterpret_cast<const vs8*>(Bp + (size_t)(t * 16) * 384 + k4 * 32);
                acc[t] = __builtin_amdgcn_mfma_f32_16x16x32_bf16(a, b, acc[t], 0, 0, 0);
            }
        }
    }
    int orow_base = row0 + kq * 4;
#pragma unroll
    for (int t = 0; t < 4; ++t) {
        int col = col0 + t * 16 + m;
        float bv = bias[col];
#pragma unroll
        for (int i = 0; i < 4; ++i) {
            int r = orow_base + i;
            if (r < NNODES) {
                float v = acc[t][i] + bv;
                v = v > 0.f ? v : 0.f;
                out[(size_t)r * 128 + col] = f2us(v);
            }
        }
    }
}

// ---- MFMA conv2 GEMM + fused mean-pool epilogue: nout=256, grid.y=4 col slabs ----
__global__ __launch_bounds__(256) void k_conv2_gemm(
    const unsigned short* seg0, const unsigned short* seg1, const unsigned short* seg2,
    const unsigned short* Wt, const float* bias, const int* batch32, float* psum) {
    int wv = threadIdx.x >> 6, lane = threadIdx.x & 63;
    int m = lane & 15, kq = lane >> 4;
    int row0 = (blockIdx.x * 4 + wv) * 16;
    int col0 = blockIdx.y * 64;
    int rr = row0 + m;
    if (rr >= NNODES) rr = NNODES - 1;
    floatx4 acc[4];
#pragma unroll
    for (int t = 0; t < 4; ++t) { acc[t][0] = 0.f; acc[t][1] = 0.f; acc[t][2] = 0.f; acc[t][3] = 0.f; }
    const unsigned short* segs[3];
    segs[0] = seg0; segs[1] = seg1; segs[2] = seg2;
#pragma unroll
    for (int sgi = 0; sgi < 3; ++sgi) {
        const unsigned short* S = segs[sgi] + (size_t)rr * 128 + kq * 8;
        const unsigned short* Bp = Wt + (size_t)(col0 + m) * 384 + sgi * 128 + kq * 8;
#pragma unroll
        for (int k4 = 0; k4 < 4; ++k4) {
            vs8 a = *reinterpret_cast<const vs8*>(S + k4 * 32);
#pragma unroll
            for (int t = 0; t < 4; ++t) {
                vs8 b = *reinterpret_cast<const vs8*>(Bp + (size_t)(t * 16) * 384 + k4 * 32);
                acc[t] = __builtin_amdgcn_mfma_f32_16x16x32_bf16(a, b, acc[t], 0, 0, 0);
            }
        }
    }
    int orow_base = row0 + kq * 4;
    int gid[4];
#pragma unroll
    for (int i = 0; i < 4; ++i) {
        int r = orow_base + i;
        gid[i] = r < NNODES ? batch32[r] : -1;
    }
#pragma unroll
    for (int t = 0; t < 4; ++t) {
        int col = col0 + t * 16 + m;
        float bv = bias[col];
        float run = 0.f;
        int curg = -1;
#pragma unroll
        for (int i = 0; i < 4; ++i) {
            int g = gid[i];
            if (g < 0) break;
            float v = acc[t][i] + bv;
            v = v > 0.f ? v : 0.f;
            if (g != curg) {
                if (curg >= 0) atomicAdd(&psum[curg * 384 + col], run);
                curg = g;
                run = 0.f;
            }
            run += v;
        }
        if (curg >= 0) atomicAdd(&psum[curg * 384 + col], run);
    }
}

__global__ void k_poolfeat(const unsigned short* featb, const int* batch32,
                           float* psum, int* pcnt) {
    int g = blockIdx.x, t = threadIdx.x;
    int lo = 0, hi = NNODES;
    while (lo < hi) { int mid = (lo + hi) >> 1; if (batch32[mid] < g) lo = mid + 1; else hi = mid; }
    int start = lo;
    hi = NNODES;
    while (lo < hi) { int mid = (lo + hi) >> 1; if (batch32[mid] <= g) lo = mid + 1; else hi = mid; }
    int end = lo;
    float acc = 0.f;
    for (int n = start; n < end; ++n) acc += us2f(featb[(size_t)n * 128 + t]);
    psum[g * 384 + 256 + t] = acc;
    if (t == 0) pcnt[g] = end - start;
}

__global__ void k_fc1(const float* psum, const int* pcnt, const float* w,
                      const float* b, float* h) {
    int g = blockIdx.x, j = threadIdx.x * 2;
    int c = pcnt[g];
    float inv = 1.f / (float)(c > 0 ? c : 1);
    float a0 = 0.f, a1 = 0.f;
    for (int k = 0; k < 384; ++k) {
        float p = psum[g * 384 + k];
        a0 += p * w[k * 512 + j];
        a1 += p * w[k * 512 + j + 1];
    }
    a0 = a0 * inv + b[j];
    a1 = a1 * inv + b[j + 1];
    h[g * 512 + j] = a0 > 0.f ? a0 : 0.f;
    h[g * 512 + j + 1] = a1 > 0.f ? a1 : 0.f;
}

// final FC2 + store — carries the harness identifier name on purpose.
__global__ void ChebModel_74380243632480_kernel(const float* h, const float* w,
                                                const float* b, const int* fflag,
                                                void* out) {
    int g = blockIdx.x, j = threadIdx.x;
    float acc = 0.f;
    for (int k = 0; k < 512; ++k) acc += h[g * 512 + k] * w[k * 128 + j];
    acc += b[j];
    if (*fflag) ((unsigned short*)out)[g * 128 + j] = f2us(acc);
    else ((float*)out)[g * 128 + j] = acc;
}

extern "C" void kernel_launch(void* const* d_in, const int* in_sizes, int n_in,
                              void* d_out, int out_size, void* d_ws, size_t ws_size,
                              hipStream_t stream) {
    const void* feature = d_in[0];
    const int* edge_index = (const int*)d_in[1];
    const int* batch = (const int*)d_in[2];
    const void* W1 = d_in[3];
    const void* b1 = d_in[4];
    const void* W2 = d_in[5];
    const void* b2 = d_in[6];
    const void* fc1w = d_in[7];
    const void* fc1b = d_in[8];
    const void* fc2w = d_in[9];
    const void* fc2b = d_in[10];

    char* ws = (char*)d_ws;
    size_t off = 0;
    int* iflag = (int*)(ws + off); off += 256;
    int* fflag = (int*)(ws + off); off += 256;
    int* deg = (int*)(ws + off); off += ((size_t)NNODES * 4 + 255) & ~(size_t)255;
    int* indeg = (int*)(ws + off); off += ((size_t)NNODES * 4 + 255) & ~(size_t)255;
    int* cursor = (int*)(ws + off); off += ((size_t)NNODES * 4 + 255) & ~(size_t)255;
    int* rowptr = (int*)(ws + off); off += ((size_t)(NNODES + 1) * 4 + 255) & ~(size_t)255;
    float* dinv = (float*)(ws + off); off += ((size_t)NNODES * 4 + 255) & ~(size_t)255;
    int* batch32 = (int*)(ws + off); off += ((size_t)NNODES * 4 + 255) & ~(size_t)255;
    int* csr_src = (int*)(ws + off); off += ((size_t)NEDGES * 4 + 255) & ~(size_t)255;
    float* csr_w = (float*)(ws + off); off += ((size_t)NEDGES * 4 + 255) & ~(size_t)255;
    unsigned short* featb = (unsigned short*)(ws + off); off += ((size_t)NNODES * 128 * 2 + 255) & ~(size_t)255;
    unsigned short* T1 = (unsigned short*)(ws + off); off += ((size_t)NNODES * 128 * 2 + 255) & ~(size_t)255;
    unsigned short* T2 = (unsigned short*)(ws + off); off += ((size_t)NNODES * 128 * 2 + 255) & ~(size_t)255;
    unsigned short* gx1 = (unsigned short*)(ws + off); off += ((size_t)NNODES * 128 * 2 + 255) & ~(size_t)255;
    unsigned short* W1t = (unsigned short*)(ws + off); off += ((size_t)49152 * 2 + 255) & ~(size_t)255;
    unsigned short* W2t = (unsigned short*)(ws + off); off += ((size_t)98304 * 2 + 255) & ~(size_t)255;
    float* b1f = (float*)(ws + off); off += 1024;
    float* b2f = (float*)(ws + off); off += 1024;
    float* fc1wf = (float*)(ws + off); off += ((size_t)196608 * 4 + 255) & ~(size_t)255;
    float* fc1bf = (float*)(ws + off); off += 2048;
    float* fc2wf = (float*)(ws + off); off += ((size_t)65536 * 4 + 255) & ~(size_t)255;
    float* fc2bf = (float*)(ws + off); off += 1024;
    float* psum = (float*)(ws + off); off += ((size_t)128 * 384 * 4 + 255) & ~(size_t)255;
    int* pcnt = (int*)(ws + off); off += 1024;
    float* hbuf = (float*)(ws + off); off += ((size_t)128 * 512 * 4 + 255) & ~(size_t)255;

    k_zero<<<(NNODES + 255) / 256, 256, 0, stream>>>(deg, indeg, psum);
    k_detect_int<<<1, 64, 0, stream>>>(edge_index, iflag);
    k_detect_float<<<1, 64, 0, stream>>>((const unsigned int*)feature, fflag);
    k_batch<<<(NNODES + 255) / 256, 256, 0, stream>>>(batch, iflag, batch32);
    k_degree<<<(NEDGES + 255) / 256, 256, 0, stream>>>(edge_index, iflag, deg, indeg);
    k_dinv<<<(NNODES + 255) / 256, 256, 0, stream>>>(deg, dinv);
    k_scan<<<1, 256, 0, stream>>>(indeg, rowptr, cursor);
    k_fill<<<(NEDGES + 255) / 256, 256, 0, stream>>>(edge_index, iflag, dinv, cursor, csr_src, csr_w);

    k_featb<<<(NNODES * 128 + 255) / 256, 256, 0, stream>>>(feature, fflag, NNODES * 128, featb);
    k_trans<<<(49152 + 255) / 256, 256, 0, stream>>>(W1, fflag, 384, 128, W1t);
    k_trans<<<(98304 + 255) / 256, 256, 0, stream>>>(W2, fflag, 384, 256, W2t);
    k_convw<<<1, 256, 0, stream>>>(b1, fflag, 128, b1f);
    k_convw<<<1, 256, 0, stream>>>(b2, fflag, 256, b2f);
    k_convw<<<(196608 + 255) / 256, 256, 0, stream>>>(fc1w, fflag, 196608, fc1wf);
    k_convw<<<2, 256, 0, stream>>>(fc1b, fflag, 512, fc1bf);
    k_convw<<<(65536 + 255) / 256, 256, 0, stream>>>(fc2w, fflag, 65536, fc2wf);
    k_convw<<<1, 256, 0, stream>>>(fc2b, fflag, 128, fc2bf);

    int pb = (NNODES * 64 + 255) / 256;
    // conv1: T1 = prop(featb), T2 = 2*prop(T1) - featb, gx1 = relu([f|T1|T2]@W1 + b1)
    k_prop<<<pb, 256, 0, stream>>>(featb, rowptr, csr_src, csr_w, (const unsigned short*)0, 1.f, 0.f, T1);
    k_prop<<<pb, 256, 0, stream>>>(T1, rowptr, csr_src, csr_w, featb, 2.f, -1.f, T2);
    {
        dim3 g1((NNODES + 63) / 64, 2);
        k_conv1_gemm<<<g1, 256, 0, stream>>>(featb, T1, T2, W1t, b1f, gx1);
    }
    // conv2 with fused mean-pool epilogue
    k_prop<<<pb, 256, 0, stream>>>(gx1, rowptr, csr_src, csr_w, (const unsigned short*)0, 1.f, 0.f, T1);
    k_prop<<<pb, 256, 0, stream>>>(T1, rowptr, csr_src, csr_w, gx1, 2.f, -1.f, T2);
    {
        dim3 g2((NNODES + 63) / 64, 4);
        k_conv2_gemm<<<g2, 256, 0, stream>>>(gx1, T1, T2, W2t, b2f, batch32, psum);
    }
    // feature part of pooling + counts, then FC head
    k_poolfeat<<<128, 128, 0, stream>>>(featb, batch32, psum, pcnt);
    k_fc1<<<128, 256, 0, stream>>>(psum, pcnt, fc1wf, fc1bf, hbuf);
    ChebModel_74380243632480_kernel<<<128, 128, 0, stream>>>(hbuf, fc2wf, fc2bf, fflag, d_out);
}

// Round 7
// 594.784 us; speedup vs baseline: 1.9216x; 1.5641x over previous
//
#include <hip/hip_runtime.h>
#include <hip/hip_bf16.h>

#define NNODES 50000
#define NEDGES 600000
#define NB 196  // ceil(NNODES/256)

typedef short vs8 __attribute__((ext_vector_type(8)));
typedef float floatx4 __attribute__((ext_vector_type(4)));

__device__ __forceinline__ float us2f(unsigned short u) {
    unsigned int x = ((unsigned int)u) << 16;
    float f;
    __builtin_memcpy(&f, &x, 4);
    return f;
}
__device__ __forceinline__ unsigned short f2us(float f) {
    unsigned int x;
    __builtin_memcpy(&x, &f, 4);
    unsigned int r = x + 0x7fffu + ((x >> 16) & 1u);  // RNE
    return (unsigned short)(r >> 16);
}

// zero scratch (no hipMemsetAsync anywhere)
__global__ void k_zero(int* deg, int* indeg, float* psum) {
    int i = blockIdx.x * blockDim.x + threadIdx.x;
    if (i < NNODES) { deg[i] = 0; indeg[i] = 0; }
    if (i < 128 * 384) psum[i] = 0.f;
}

// int64-vs-int32 storage detection on edge_index (LE int64 => odd words 0)
__global__ void k_detect_int(const int* ei, int* iflag) {
    if (threadIdx.x == 0 && blockIdx.x == 0) {
        int f = 1;
        for (int i = 1; i < 256; i += 2)
            if (ei[i] != 0) f = 0;
        *iflag = f;
    }
}

// fp32-vs-bf16 storage detection on feature
__global__ void k_detect_float(const unsigned int* fw, int* fflag) {
    if (threadIdx.x == 0 && blockIdx.x == 0) {
        int hits = 0;
        for (int i = 0; i < 128; ++i) {
            unsigned int e = (fw[i] >> 7) & 0xffu;
            if (e > 100u && e < 160u) hits++;
        }
        *fflag = (hits > 80) ? 1 : 0;  // 1 = bf16 storage, 0 = fp32 storage
    }
}

__global__ void k_batch(const int* pb, const int* iflag, int* b32) {
    int i = blockIdx.x * blockDim.x + threadIdx.x;
    if (i >= NNODES) return;
    int f = *iflag;
    b32[i] = pb[((size_t)i) << f];
}

__global__ void k_degree(const int* ei, const int* iflag, int* deg, int* indeg) {
    int e = blockIdx.x * blockDim.x + threadIdx.x;
    if (e >= NEDGES) return;
    int f = *iflag;
    int s = ei[((size_t)e) << f];
    int d = ei[((size_t)(NEDGES + e)) << f];
    atomicAdd(&deg[s], 1);
    atomicAdd(&indeg[d], 1);
}

__global__ void k_dinv(const int* deg, float* dinv) {
    int i = blockIdx.x * blockDim.x + threadIdx.x;
    if (i >= NNODES) return;
    int d = deg[i];
    dinv[i] = d > 0 ? rsqrtf((float)d) : 0.f;
}

// ---- hierarchical scan: block sums -> scan sums -> block-local scan + offset ----
__global__ void k_scan1(const int* indeg, int* bsum) {
    __shared__ int sh[256];
    int t = threadIdx.x;
    int i = blockIdx.x * 256 + t;
    int v = (i < NNODES) ? indeg[i] : 0;
    sh[t] = v;
    __syncthreads();
    for (int off = 128; off > 0; off >>= 1) {
        if (t < off) sh[t] += sh[t + off];
        __syncthreads();
    }
    if (t == 0) bsum[blockIdx.x] = sh[0];
}

__global__ void k_scan2(const int* bsum, int* boff, int* rowptr) {
    __shared__ int sh[256];
    int t = threadIdx.x;
    int v = (t < NB) ? bsum[t] : 0;
    sh[t] = v;
    __syncthreads();
    for (int off = 1; off < 256; off <<= 1) {
        int x = (t >= off) ? sh[t - off] : 0;
        __syncthreads();
        sh[t] += x;
        __syncthreads();
    }
    if (t < NB) boff[t] = sh[t] - v;  // exclusive
    if (t == 255) rowptr[NNODES] = sh[255];
}

__global__ void k_scan3(const int* indeg, const int* boff, int* rowptr, int* cursor) {
    __shared__ int sh[256];
    int t = threadIdx.x;
    int i = blockIdx.x * 256 + t;
    int v = (i < NNODES) ? indeg[i] : 0;
    sh[t] = v;
    __syncthreads();
    for (int off = 1; off < 256; off <<= 1) {
        int x = (t >= off) ? sh[t - off] : 0;
        __syncthreads();
        sh[t] += x;
        __syncthreads();
    }
    int excl = sh[t] - v + boff[blockIdx.x];
    if (i < NNODES) { rowptr[i] = excl; cursor[i] = excl; }
}

__global__ void k_fill(const int* ei, const int* iflag, const float* dinv,
                       int* cursor, int* csr_src, float* csr_w) {
    int e = blockIdx.x * blockDim.x + threadIdx.x;
    if (e >= NEDGES) return;
    int f = *iflag;
    int s = ei[((size_t)e) << f];
    int d = ei[((size_t)(NEDGES + e)) << f];
    float w = -dinv[s] * dinv[d];
    int p = atomicAdd(&cursor[d], 1);
    csr_src[p] = s;
    csr_w[p] = w;
}

// canonicalize feature to bf16 shorts regardless of storage dtype
__global__ void k_featb(const void* src, const int* fflag, int n, unsigned short* dst) {
    int i = blockIdx.x * blockDim.x + threadIdx.x;
    if (i >= n) return;
    if (*fflag) dst[i] = ((const unsigned short*)src)[i];
    else dst[i] = f2us(((const float*)src)[i]);
}

// weights/biases to fp32 regardless of storage dtype
__global__ void k_convw(const void* src, const int* fflag, int n, float* dst) {
    int i = blockIdx.x * blockDim.x + threadIdx.x;
    if (i >= n) return;
    if (*fflag) dst[i] = us2f(((const unsigned short*)src)[i]);
    else dst[i] = ((const float*)src)[i];
}

// transpose conv weight [ktot][nout] -> bf16 [nout][ktot]
__global__ void k_trans(const void* src, const int* fflag, int ktot, int nout,
                        unsigned short* dst) {
    int idx = blockIdx.x * blockDim.x + threadIdx.x;
    if (idx >= ktot * nout) return;
    int n = idx / ktot, k = idx - n * ktot;
    if (*fflag) dst[idx] = ((const unsigned short*)src)[k * nout + n];
    else dst[idx] = f2us(((const float*)src)[k * nout + n]);
}

// out[n,:] = ascale * sum_{e into n} w_e * X[src_e,:] + sscale * sub[n,:]   (bf16 storage)
// unroll-4 with explicit index prefetch: 4 independent row-gathers in flight
__global__ void k_prop(const unsigned short* X, const int* rowptr, const int* csr_src,
                       const float* csr_w, const unsigned short* sub,
                       float ascale, float sscale, unsigned short* out) {
    int wid = (blockIdx.x * blockDim.x + threadIdx.x) >> 6;
    int lane = threadIdx.x & 63;
    if (wid >= NNODES) return;
    int beg = rowptr[wid], end = rowptr[wid + 1];
    int f = lane * 2;
    float ax = 0.f, ay = 0.f;
    int j = beg;
    for (; j + 4 <= end; j += 4) {
        int s0 = csr_src[j], s1 = csr_src[j + 1], s2 = csr_src[j + 2], s3 = csr_src[j + 3];
        float w0 = csr_w[j], w1 = csr_w[j + 1], w2 = csr_w[j + 2], w3 = csr_w[j + 3];
        unsigned int u0 = *reinterpret_cast<const unsigned int*>(X + (size_t)s0 * 128 + f);
        unsigned int u1 = *reinterpret_cast<const unsigned int*>(X + (size_t)s1 * 128 + f);
        unsigned int u2 = *reinterpret_cast<const unsigned int*>(X + (size_t)s2 * 128 + f);
        unsigned int u3 = *reinterpret_cast<const unsigned int*>(X + (size_t)s3 * 128 + f);
        ax += w0 * us2f((unsigned short)(u0 & 0xffffu));
        ay += w0 * us2f((unsigned short)(u0 >> 16));
        ax += w1 * us2f((unsigned short)(u1 & 0xffffu));
        ay += w1 * us2f((unsigned short)(u1 >> 16));
        ax += w2 * us2f((unsigned short)(u2 & 0xffffu));
        ay += w2 * us2f((unsigned short)(u2 >> 16));
        ax += w3 * us2f((unsigned short)(u3 & 0xffffu));
        ay += w3 * us2f((unsigned short)(u3 >> 16));
    }
    for (; j < end; ++j) {
        int s = csr_src[j];
        float w = csr_w[j];
        unsigned int u = *reinterpret_cast<const unsigned int*>(X + (size_t)s * 128 + f);
        ax += w * us2f((unsigned short)(u & 0xffffu));
        ay += w * us2f((unsigned short)(u >> 16));
    }
    float ox = ascale * ax, oy = ascale * ay;
    if (sub != 0) {
        unsigned int u = *reinterpret_cast<const unsigned int*>(sub + (size_t)wid * 128 + f);
        ox += sscale * us2f((unsigned short)(u & 0xffffu));
        oy += sscale * us2f((unsigned short)(u >> 16));
    }
    unsigned int ov = ((unsigned int)f2us(oy) << 16) | (unsigned int)f2us(ox);
    *reinterpret_cast<unsigned int*>(out + (size_t)wid * 128 + f) = ov;
}

// ---- MFMA conv GEMM with LDS-staged B ----
// Block: 512 threads (8 waves), covers 256 rows x 64 cols. B slab (64 cols x 384 k)
// staged in LDS with stride 392 shorts (784B = 49 dwords*16 -> 2-way-max banking).
// Wave: 32 rows (2 A-frags) x 64 cols (4 B-frags), acc[2][4].
// pool=0: bf16 store to out (row stride nout). pool=1: per-graph atomics into psum.
__global__ __launch_bounds__(512) void k_convg(
    const unsigned short* seg0, const unsigned short* seg1, const unsigned short* seg2,
    const unsigned short* Wt, const float* bias, unsigned short* out,
    const int* batch32, float* psum, int nout, int pool) {
    extern __shared__ unsigned short shb[];  // 64 * 392 shorts = 50176 B
    int tid = threadIdx.x;
    int col0 = blockIdx.y * 64;
    // cooperative B-slab stage: 3072 vec8 chunks over 512 threads
#pragma unroll
    for (int it = 0; it < 6; ++it) {
        int idx = tid + it * 512;
        int c = idx / 48, jc = idx - c * 48;
        uint4 v = *reinterpret_cast<const uint4*>(Wt + (size_t)(col0 + c) * 384 + jc * 8);
        *reinterpret_cast<uint4*>(shb + c * 392 + jc * 8) = v;
    }
    __syncthreads();
    int wv = tid >> 6, lane = tid & 63;
    int m = lane & 15, kq = lane >> 4;
    int row0 = blockIdx.x * 256 + wv * 32;
    int rr0 = row0 + m;
    int rr1 = row0 + 16 + m;
    if (rr0 >= NNODES) rr0 = NNODES - 1;
    if (rr1 >= NNODES) rr1 = NNODES - 1;
    floatx4 acc[2][4];
#pragma unroll
    for (int r = 0; r < 2; ++r)
#pragma unroll
        for (int t = 0; t < 4; ++t) {
            acc[r][t][0] = 0.f; acc[r][t][1] = 0.f; acc[r][t][2] = 0.f; acc[r][t][3] = 0.f;
        }
    const unsigned short* segs[3];
    segs[0] = seg0; segs[1] = seg1; segs[2] = seg2;
#pragma unroll
    for (int kk = 0; kk < 12; ++kk) {
        int sgi = kk >> 2, k4 = kk & 3;
        const unsigned short* S = segs[sgi];
        int ko = k4 * 32 + kq * 8;
        vs8 a0 = *reinterpret_cast<const vs8*>(S + (size_t)rr0 * 128 + ko);
        vs8 a1 = *reinterpret_cast<const vs8*>(S + (size_t)rr1 * 128 + ko);
        int lo = kk * 32 + kq * 8;
#pragma unroll
        for (int t = 0; t < 4; ++t) {
            vs8 b = *reinterpret_cast<const vs8*>(shb + (t * 16 + m) * 392 + lo);
            acc[0][t] = __builtin_amdgcn_mfma_f32_16x16x32_bf16(a0, b, acc[0][t], 0, 0, 0);
            acc[1][t] = __builtin_amdgcn_mfma_f32_16x16x32_bf16(a1, b, acc[1][t], 0, 0, 0);
        }
    }
    if (pool == 0) {
#pragma unroll
        for (int r = 0; r < 2; ++r) {
            int orow_base = row0 + r * 16 + kq * 4;
#pragma unroll
            for (int t = 0; t < 4; ++t) {
                int col = col0 + t * 16 + m;
                float bv = bias[col];
#pragma unroll
                for (int i = 0; i < 4; ++i) {
                    int rw = orow_base + i;
                    if (rw < NNODES) {
                        float v = acc[r][t][i] + bv;
                        v = v > 0.f ? v : 0.f;
                        out[(size_t)rw * nout + col] = f2us(v);
                    }
                }
            }
        }
    } else {
#pragma unroll
        for (int r = 0; r < 2; ++r) {
            int orow_base = row0 + r * 16 + kq * 4;
            int gid[4];
#pragma unroll
            for (int i = 0; i < 4; ++i) {
                int rw = orow_base + i;
                gid[i] = rw < NNODES ? batch32[rw] : -1;
            }
#pragma unroll
            for (int t = 0; t < 4; ++t) {
                int col = col0 + t * 16 + m;
                float bv = bias[col];
                float run = 0.f;
                int curg = -1;
#pragma unroll
                for (int i = 0; i < 4; ++i) {
                    int g = gid[i];
                    if (g < 0) break;
                    float v = acc[r][t][i] + bv;
                    v = v > 0.f ? v : 0.f;
                    if (g != curg) {
                        if (curg >= 0) atomicAdd(&psum[curg * 384 + col], run);
                        curg = g;
                        run = 0.f;
                    }
                    run += v;
                }
                if (curg >= 0) atomicAdd(&psum[curg * 384 + col], run);
            }
        }
    }
}

__global__ void k_poolfeat(const unsigned short* featb, const int* batch32,
                           float* psum, int* pcnt) {
    int g = blockIdx.x, t = threadIdx.x;
    int lo = 0, hi = NNODES;
    while (lo < hi) { int mid = (lo + hi) >> 1; if (batch32[mid] < g) lo = mid + 1; else hi = mid; }
    int start = lo;
    hi = NNODES;
    while (lo < hi) { int mid = (lo + hi) >> 1; if (batch32[mid] <= g) lo = mid + 1; else hi = mid; }
    int end = lo;
    float acc = 0.f;
    for (int n = start; n < end; ++n) acc += us2f(featb[(size_t)n * 128 + t]);
    psum[g * 384 + 256 + t] = acc;
    if (t == 0) pcnt[g] = end - start;
}

__global__ void k_fc1(const float* psum, const int* pcnt, const float* w,
                      const float* b, float* h) {
    int g = blockIdx.x, j = threadIdx.x * 2;
    int c = pcnt[g];
    float inv = 1.f / (float)(c > 0 ? c : 1);
    float a0 = 0.f, a1 = 0.f;
    for (int k = 0; k < 384; ++k) {
        float p = psum[g * 384 + k];
        a0 += p * w[k * 512 + j];
        a1 += p * w[k * 512 + j + 1];
    }
    a0 = a0 * inv + b[j];
    a1 = a1 * inv + b[j + 1];
    h[g * 512 + j] = a0 > 0.f ? a0 : 0.f;
    h[g * 512 + j + 1] = a1 > 0.f ? a1 : 0.f;
}

// final FC2 + store — carries the harness identifier name on purpose.
__global__ void ChebModel_74380243632480_kernel(const float* h, const float* w,
                                                const float* b, const int* fflag,
                                                void* out) {
    int g = blockIdx.x, j = threadIdx.x;
    float acc = 0.f;
    for (int k = 0; k < 512; ++k) acc += h[g * 512 + k] * w[k * 128 + j];
    acc += b[j];
    if (*fflag) ((unsigned short*)out)[g * 128 + j] = f2us(acc);
    else ((float*)out)[g * 128 + j] = acc;
}

extern "C" void kernel_launch(void* const* d_in, const int* in_sizes, int n_in,
                              void* d_out, int out_size, void* d_ws, size_t ws_size,
                              hipStream_t stream) {
    const void* feature = d_in[0];
    const int* edge_index = (const int*)d_in[1];
    const int* batch = (const int*)d_in[2];
    const void* W1 = d_in[3];
    const void* b1 = d_in[4];
    const void* W2 = d_in[5];
    const void* b2 = d_in[6];
    const void* fc1w = d_in[7];
    const void* fc1b = d_in[8];
    const void* fc2w = d_in[9];
    const void* fc2b = d_in[10];

    char* ws = (char*)d_ws;
    size_t off = 0;
    int* iflag = (int*)(ws + off); off += 256;
    int* fflag = (int*)(ws + off); off += 256;
    int* deg = (int*)(ws + off); off += ((size_t)NNODES * 4 + 255) & ~(size_t)255;
    int* indeg = (int*)(ws + off); off += ((size_t)NNODES * 4 + 255) & ~(size_t)255;
    int* cursor = (int*)(ws + off); off += ((size_t)NNODES * 4 + 255) & ~(size_t)255;
    int* rowptr = (int*)(ws + off); off += ((size_t)(NNODES + 1) * 4 + 255) & ~(size_t)255;
    float* dinv = (float*)(ws + off); off += ((size_t)NNODES * 4 + 255) & ~(size_t)255;
    int* batch32 = (int*)(ws + off); off += ((size_t)NNODES * 4 + 255) & ~(size_t)255;
    int* bsum = (int*)(ws + off); off += 1024;
    int* boff = (int*)(ws + off); off += 1024;
    int* csr_src = (int*)(ws + off); off += ((size_t)NEDGES * 4 + 255) & ~(size_t)255;
    float* csr_w = (float*)(ws + off); off += ((size_t)NEDGES * 4 + 255) & ~(size_t)255;
    unsigned short* featb = (unsigned short*)(ws + off); off += ((size_t)NNODES * 128 * 2 + 255) & ~(size_t)255;
    unsigned short* T1 = (unsigned short*)(ws + off); off += ((size_t)NNODES * 128 * 2 + 255) & ~(size_t)255;
    unsigned short* T2 = (unsigned short*)(ws + off); off += ((size_t)NNODES * 128 * 2 + 255) & ~(size_t)255;
    unsigned short* gx1 = (unsigned short*)(ws + off); off += ((size_t)NNODES * 128 * 2 + 255) & ~(size_t)255;
    unsigned short* W1t = (unsigned short*)(ws + off); off += ((size_t)49152 * 2 + 255) & ~(size_t)255;
    unsigned short* W2t = (unsigned short*)(ws + off); off += ((size_t)98304 * 2 + 255) & ~(size_t)255;
    float* b1f = (float*)(ws + off); off += 1024;
    float* b2f = (float*)(ws + off); off += 1024;
    float* fc1wf = (float*)(ws + off); off += ((size_t)196608 * 4 + 255) & ~(size_t)255;
    float* fc1bf = (float*)(ws + off); off += 2048;
    float* fc2wf = (float*)(ws + off); off += ((size_t)65536 * 4 + 255) & ~(size_t)255;
    float* fc2bf = (float*)(ws + off); off += 1024;
    float* psum = (float*)(ws + off); off += ((size_t)128 * 384 * 4 + 255) & ~(size_t)255;
    int* pcnt = (int*)(ws + off); off += 1024;
    float* hbuf = (float*)(ws + off); off += ((size_t)128 * 512 * 4 + 255) & ~(size_t)255;

    k_zero<<<(NNODES + 255) / 256, 256, 0, stream>>>(deg, indeg, psum);
    k_detect_int<<<1, 64, 0, stream>>>(edge_index, iflag);
    k_detect_float<<<1, 64, 0, stream>>>((const unsigned int*)feature, fflag);
    k_batch<<<(NNODES + 255) / 256, 256, 0, stream>>>(batch, iflag, batch32);
    k_degree<<<(NEDGES + 255) / 256, 256, 0, stream>>>(edge_index, iflag, deg, indeg);
    k_dinv<<<(NNODES + 255) / 256, 256, 0, stream>>>(deg, dinv);
    k_scan1<<<NB, 256, 0, stream>>>(indeg, bsum);
    k_scan2<<<1, 256, 0, stream>>>(bsum, boff, rowptr);
    k_scan3<<<NB, 256, 0, stream>>>(indeg, boff, rowptr, cursor);
    k_fill<<<(NEDGES + 255) / 256, 256, 0, stream>>>(edge_index, iflag, dinv, cursor, csr_src, csr_w);

    k_featb<<<(NNODES * 128 + 255) / 256, 256, 0, stream>>>(feature, fflag, NNODES * 128, featb);
    k_trans<<<(49152 + 255) / 256, 256, 0, stream>>>(W1, fflag, 384, 128, W1t);
    k_trans<<<(98304 + 255) / 256, 256, 0, stream>>>(W2, fflag, 384, 256, W2t);
    k_convw<<<1, 256, 0, stream>>>(b1, fflag, 128, b1f);
    k_convw<<<1, 256, 0, stream>>>(b2, fflag, 256, b2f);
    k_convw<<<(196608 + 255) / 256, 256, 0, stream>>>(fc1w, fflag, 196608, fc1wf);
    k_convw<<<2, 256, 0, stream>>>(fc1b, fflag, 512, fc1bf);
    k_convw<<<(65536 + 255) / 256, 256, 0, stream>>>(fc2w, fflag, 65536, fc2wf);
    k_convw<<<1, 256, 0, stream>>>(fc2b, fflag, 128, fc2bf);

    int pb = (NNODES * 64 + 255) / 256;
    size_t shbytes = 64 * 392 * 2;  // 50176 B
    // conv1: T1 = prop(featb), T2 = 2*prop(T1) - featb, gx1 = relu([f|T1|T2]@W1 + b1)
    k_prop<<<pb, 256, 0, stream>>>(featb, rowptr, csr_src, csr_w, (const unsigned short*)0, 1.f, 0.f, T1);
    k_prop<<<pb, 256, 0, stream>>>(T1, rowptr, csr_src, csr_w, featb, 2.f, -1.f, T2);
    {
        dim3 g1((NNODES + 255) / 256, 2);
        k_convg<<<g1, 512, shbytes, stream>>>(featb, T1, T2, W1t, b1f, gx1,
                                              (const int*)0, (float*)0, 128, 0);
    }
    // conv2 with fused mean-pool epilogue
    k_prop<<<pb, 256, 0, stream>>>(gx1, rowptr, csr_src, csr_w, (const unsigned short*)0, 1.f, 0.f, T1);
    k_prop<<<pb, 256, 0, stream>>>(T1, rowptr, csr_src, csr_w, gx1, 2.f, -1.f, T2);
    {
        dim3 g2((NNODES + 255) / 256, 4);
        k_convg<<<g2, 512, shbytes, stream>>>(gx1, T1, T2, W2t, b2f, (unsigned short*)0,
                                              batch32, psum, 256, 1);
    }
    // feature part of pooling + counts, then FC head
    k_poolfeat<<<128, 128, 0, stream>>>(featb, batch32, psum, pcnt);
    k_fc1<<<128, 256, 0, stream>>>(psum, pcnt, fc1wf, fc1bf, hbuf);
    ChebModel_74380243632480_kernel<<<128, 128, 0, stream>>>(hbuf, fc2wf, fc2bf, fflag, d_out);
}

// Round 8
// 487.875 us; speedup vs baseline: 2.3427x; 1.2191x over previous
//
#include <hip/hip_runtime.h>
#include <hip/hip_bf16.h>

#define NNODES 50000
#define NEDGES 600000
#define NB 196  // ceil(NNODES/256)

typedef short vs8 __attribute__((ext_vector_type(8)));
typedef float floatx4 __attribute__((ext_vector_type(4)));

__device__ __forceinline__ float us2f(unsigned short u) {
    unsigned int x = ((unsigned int)u) << 16;
    float f;
    __builtin_memcpy(&f, &x, 4);
    return f;
}
__device__ __forceinline__ unsigned short f2us(float f) {
    unsigned int x;
    __builtin_memcpy(&x, &f, 4);
    unsigned int r = x + 0x7fffu + ((x >> 16) & 1u);  // RNE
    return (unsigned short)(r >> 16);
}
__device__ __forceinline__ float ldf(const void* p, int i, int ff) {
    if (ff) return us2f(((const unsigned short*)p)[i]);
    return ((const float*)p)[i];
}

// ---- dtype detection (int64-vs-int32 edges; bf16-vs-fp32 floats) ----
__global__ void k_detect(const int* ei, const unsigned int* fw, int* iflag, int* fflag) {
    if (threadIdx.x == 0) {
        int f = 1;
        for (int i = 1; i < 256; i += 2)
            if (ei[i] != 0) f = 0;
        *iflag = f;
    } else if (threadIdx.x == 1) {
        int hits = 0;
        for (int i = 0; i < 128; ++i) {
            unsigned int e = (fw[i] >> 7) & 0xffu;
            if (e > 100u && e < 160u) hits++;
        }
        *fflag = (hits > 80) ? 1 : 0;  // 1 = bf16 storage
    }
}

// zero counters + convert batch (no hipMemsetAsync anywhere)
__global__ void k_init(const int* pb, const int* iflag, int* deg, int* indeg,
                       int* b32, float* psum) {
    int i = blockIdx.x * 256 + threadIdx.x;
    if (i < NNODES) {
        deg[i] = 0;
        indeg[i] = 0;
        int f = *iflag;
        b32[i] = pb[((size_t)i) << f];
    }
    if (i < 128 * 384) psum[i] = 0.f;
}

__global__ void k_degree(const int* ei, const int* iflag, int* deg, int* indeg) {
    int e = blockIdx.x * blockDim.x + threadIdx.x;
    if (e >= NEDGES) return;
    int f = *iflag;
    int s = ei[((size_t)e) << f];
    int d = ei[((size_t)(NEDGES + e)) << f];
    atomicAdd(&deg[s], 1);
    atomicAdd(&indeg[d], 1);
}

// block sums of indeg + dinv from deg
__global__ void k_scan1(const int* indeg, const int* deg, int* bsum, float* dinv) {
    __shared__ int sh[256];
    int t = threadIdx.x;
    int i = blockIdx.x * 256 + t;
    int v = (i < NNODES) ? indeg[i] : 0;
    if (i < NNODES) {
        int d = deg[i];
        dinv[i] = d > 0 ? rsqrtf((float)d) : 0.f;
    }
    sh[t] = v;
    __syncthreads();
    for (int off = 128; off > 0; off >>= 1) {
        if (t < off) sh[t] += sh[t + off];
        __syncthreads();
    }
    if (t == 0) bsum[blockIdx.x] = sh[0];
}

// scan of block sums + per-graph node counts
__global__ void k_scan2(const int* bsum, int* boff, int* rowptr,
                        const int* batch32, int* pcnt) {
    __shared__ int sh[256];
    int t = threadIdx.x;
    int v = (t < NB) ? bsum[t] : 0;
    sh[t] = v;
    __syncthreads();
    for (int off = 1; off < 256; off <<= 1) {
        int x = (t >= off) ? sh[t - off] : 0;
        __syncthreads();
        sh[t] += x;
        __syncthreads();
    }
    if (t < NB) boff[t] = sh[t] - v;  // exclusive
    if (t == 255) rowptr[NNODES] = sh[255];
    if (t < 128) {
        int g = t;
        int lo = 0, hi = NNODES;
        while (lo < hi) { int mid = (lo + hi) >> 1; if (batch32[mid] < g) lo = mid + 1; else hi = mid; }
        int start = lo;
        hi = NNODES;
        while (lo < hi) { int mid = (lo + hi) >> 1; if (batch32[mid] <= g) lo = mid + 1; else hi = mid; }
        pcnt[g] = lo - start;
    }
}

__global__ void k_scan3(const int* indeg, const int* boff, int* rowptr, int* cursor) {
    __shared__ int sh[256];
    int t = threadIdx.x;
    int i = blockIdx.x * 256 + t;
    int v = (i < NNODES) ? indeg[i] : 0;
    sh[t] = v;
    __syncthreads();
    for (int off = 1; off < 256; off <<= 1) {
        int x = (t >= off) ? sh[t - off] : 0;
        __syncthreads();
        sh[t] += x;
        __syncthreads();
    }
    int excl = sh[t] - v + boff[blockIdx.x];
    if (i < NNODES) { rowptr[i] = excl; cursor[i] = excl; }
}

__global__ void k_fill(const int* ei, const int* iflag, const float* dinv,
                       int* cursor, int* csr_src, float* csr_w) {
    int e = blockIdx.x * blockDim.x + threadIdx.x;
    if (e >= NEDGES) return;
    int f = *iflag;
    int s = ei[((size_t)e) << f];
    int d = ei[((size_t)(NEDGES + e)) << f];
    float w = -dinv[s] * dinv[d];
    int p = atomicAdd(&cursor[d], 1);
    csr_src[p] = s;
    csr_w[p] = w;
}

// canonicalize feature -> bf16, 8 shorts (16B) per thread
__global__ void k_featb(const void* src, const int* fflag, unsigned short* dst) {
    int i = blockIdx.x * 256 + threadIdx.x;  // chunk of 8 shorts
    if (i >= NNODES * 128 / 8) return;
    if (*fflag) {
        reinterpret_cast<uint4*>(dst)[i] = reinterpret_cast<const uint4*>(src)[i];
    } else {
        const float4* fs = reinterpret_cast<const float4*>(src);
        float4 a = fs[2 * i], b = fs[2 * i + 1];
        uint4 o;
        o.x = (unsigned int)f2us(a.x) | ((unsigned int)f2us(a.y) << 16);
        o.y = (unsigned int)f2us(a.z) | ((unsigned int)f2us(a.w) << 16);
        o.z = (unsigned int)f2us(b.x) | ((unsigned int)f2us(b.y) << 16);
        o.w = (unsigned int)f2us(b.z) | ((unsigned int)f2us(b.w) << 16);
        reinterpret_cast<uint4*>(dst)[i] = o;
    }
}

// both conv weight transposes in one launch: [384][nout] -> bf16 [nout][384]
__global__ void k_trans2(const void* W1, const void* W2, const int* fflag,
                         unsigned short* W1t, unsigned short* W2t) {
    int idx = blockIdx.x * 256 + threadIdx.x;
    int ff = *fflag;
    if (idx < 49152) {
        int n = idx / 384, k = idx - n * 384;
        float v = ldf(W1, k * 128 + n, ff);
        W1t[idx] = f2us(v);
    } else if (idx < 49152 + 98304) {
        int j = idx - 49152;
        int n = j / 384, k = j - n * 384;
        float v = ldf(W2, k * 256 + n, ff);
        W2t[j] = f2us(v);
    }
}

// all FC weights/biases -> fp32, one launch (263168 elements)
__global__ void k_prepw(const void* b1, const void* b2, const void* f1w, const void* f1b,
                        const void* f2w, const void* f2b, const int* fflag,
                        float* b1f, float* b2f, float* f1wf, float* f1bf,
                        float* f2wf, float* f2bf) {
    int i = blockIdx.x * 256 + threadIdx.x;
    int ff = *fflag;
    if (i < 196608) { f1wf[i] = ldf(f1w, i, ff); return; }
    i -= 196608;
    if (i < 65536) { f2wf[i] = ldf(f2w, i, ff); return; }
    i -= 65536;
    if (i < 512) { f1bf[i] = ldf(f1b, i, ff); return; }
    i -= 512;
    if (i < 256) { b2f[i] = ldf(b2, i, ff); return; }
    i -= 256;
    if (i < 128) { b1f[i] = ldf(b1, i, ff); return; }
    i -= 128;
    if (i < 128) f2bf[i] = ldf(f2b, i, ff);
}

// out[n,:] = ascale * sum_{e into n} w_e * X[src_e,:] + sscale * sub[n,:]
// unroll-8: 8 independent row-gathers in flight per wave
__global__ void k_prop(const unsigned short* X, const int* rowptr, const int* csr_src,
                       const float* csr_w, const unsigned short* sub,
                       float ascale, float sscale, unsigned short* out) {
    int wid = (blockIdx.x * blockDim.x + threadIdx.x) >> 6;
    int lane = threadIdx.x & 63;
    if (wid >= NNODES) return;
    int beg = rowptr[wid], end = rowptr[wid + 1];
    int f = lane * 2;
    float ax = 0.f, ay = 0.f;
    int j = beg;
    for (; j + 8 <= end; j += 8) {
        int s[8];
        float w[8];
        unsigned int u[8];
#pragma unroll
        for (int q = 0; q < 8; ++q) { s[q] = csr_src[j + q]; w[q] = csr_w[j + q]; }
#pragma unroll
        for (int q = 0; q < 8; ++q)
            u[q] = *reinterpret_cast<const unsigned int*>(X + (size_t)s[q] * 128 + f);
#pragma unroll
        for (int q = 0; q < 8; ++q) {
            ax += w[q] * us2f((unsigned short)(u[q] & 0xffffu));
            ay += w[q] * us2f((unsigned short)(u[q] >> 16));
        }
    }
    for (; j + 2 <= end; j += 2) {
        int s0 = csr_src[j], s1 = csr_src[j + 1];
        float w0 = csr_w[j], w1 = csr_w[j + 1];
        unsigned int u0 = *reinterpret_cast<const unsigned int*>(X + (size_t)s0 * 128 + f);
        unsigned int u1 = *reinterpret_cast<const unsigned int*>(X + (size_t)s1 * 128 + f);
        ax += w0 * us2f((unsigned short)(u0 & 0xffffu));
        ay += w0 * us2f((unsigned short)(u0 >> 16));
        ax += w1 * us2f((unsigned short)(u1 & 0xffffu));
        ay += w1 * us2f((unsigned short)(u1 >> 16));
    }
    for (; j < end; ++j) {
        int s = csr_src[j];
        float w = csr_w[j];
        unsigned int u = *reinterpret_cast<const unsigned int*>(X + (size_t)s * 128 + f);
        ax += w * us2f((unsigned short)(u & 0xffffu));
        ay += w * us2f((unsigned short)(u >> 16));
    }
    float ox = ascale * ax, oy = ascale * ay;
    if (sub != 0) {
        unsigned int u = *reinterpret_cast<const unsigned int*>(sub + (size_t)wid * 128 + f);
        ox += sscale * us2f((unsigned short)(u & 0xffffu));
        oy += sscale * us2f((unsigned short)(u >> 16));
    }
    unsigned int ov = ((unsigned int)f2us(oy) << 16) | (unsigned int)f2us(ox);
    *reinterpret_cast<unsigned int*>(out + (size_t)wid * 128 + f) = ov;
}

// ---- MFMA conv GEMM with LDS-staged B (unchanged from round 7) ----
__global__ __launch_bounds__(512) void k_convg(
    const unsigned short* seg0, const unsigned short* seg1, const unsigned short* seg2,
    const unsigned short* Wt, const float* bias, unsigned short* out,
    const int* batch32, float* psum, int nout, int pool) {
    extern __shared__ unsigned short shb[];  // 64 * 392 shorts = 50176 B
    int tid = threadIdx.x;
    int col0 = blockIdx.y * 64;
#pragma unroll
    for (int it = 0; it < 6; ++it) {
        int idx = tid + it * 512;
        int c = idx / 48, jc = idx - c * 48;
        uint4 v = *reinterpret_cast<const uint4*>(Wt + (size_t)(col0 + c) * 384 + jc * 8);
        *reinterpret_cast<uint4*>(shb + c * 392 + jc * 8) = v;
    }
    __syncthreads();
    int wv = tid >> 6, lane = tid & 63;
    int m = lane & 15, kq = lane >> 4;
    int row0 = blockIdx.x * 256 + wv * 32;
    int rr0 = row0 + m;
    int rr1 = row0 + 16 + m;
    if (rr0 >= NNODES) rr0 = NNODES - 1;
    if (rr1 >= NNODES) rr1 = NNODES - 1;
    floatx4 acc[2][4];
#pragma unroll
    for (int r = 0; r < 2; ++r)
#pragma unroll
        for (int t = 0; t < 4; ++t) {
            acc[r][t][0] = 0.f; acc[r][t][1] = 0.f; acc[r][t][2] = 0.f; acc[r][t][3] = 0.f;
        }
    const unsigned short* segs[3];
    segs[0] = seg0; segs[1] = seg1; segs[2] = seg2;
#pragma unroll
    for (int kk = 0; kk < 12; ++kk) {
        int sgi = kk >> 2, k4 = kk & 3;
        const unsigned short* S = segs[sgi];
        int ko = k4 * 32 + kq * 8;
        vs8 a0 = *reinterpret_cast<const vs8*>(S + (size_t)rr0 * 128 + ko);
        vs8 a1 = *reinterpret_cast<const vs8*>(S + (size_t)rr1 * 128 + ko);
        int lo = kk * 32 + kq * 8;
#pragma unroll
        for (int t = 0; t < 4; ++t) {
            vs8 b = *reinterpret_cast<const vs8*>(shb + (t * 16 + m) * 392 + lo);
            acc[0][t] = __builtin_amdgcn_mfma_f32_16x16x32_bf16(a0, b, acc[0][t], 0, 0, 0);
            acc[1][t] = __builtin_amdgcn_mfma_f32_16x16x32_bf16(a1, b, acc[1][t], 0, 0, 0);
        }
    }
    if (pool == 0) {
#pragma unroll
        for (int r = 0; r < 2; ++r) {
            int orow_base = row0 + r * 16 + kq * 4;
#pragma unroll
            for (int t = 0; t < 4; ++t) {
                int col = col0 + t * 16 + m;
                float bv = bias[col];
#pragma unroll
                for (int i = 0; i < 4; ++i) {
                    int rw = orow_base + i;
                    if (rw < NNODES) {
                        float v = acc[r][t][i] + bv;
                        v = v > 0.f ? v : 0.f;
                        out[(size_t)rw * nout + col] = f2us(v);
                    }
                }
            }
        }
    } else {
#pragma unroll
        for (int r = 0; r < 2; ++r) {
            int orow_base = row0 + r * 16 + kq * 4;
            int gid[4];
#pragma unroll
            for (int i = 0; i < 4; ++i) {
                int rw = orow_base + i;
                gid[i] = rw < NNODES ? batch32[rw] : -1;
            }
#pragma unroll
            for (int t = 0; t < 4; ++t) {
                int col = col0 + t * 16 + m;
                float bv = bias[col];
                float run = 0.f;
                int curg = -1;
#pragma unroll
                for (int i = 0; i < 4; ++i) {
                    int g = gid[i];
                    if (g < 0) break;
                    float v = acc[r][t][i] + bv;
                    v = v > 0.f ? v : 0.f;
                    if (g != curg) {
                        if (curg >= 0) atomicAdd(&psum[curg * 384 + col], run);
                        curg = g;
                        run = 0.f;
                    }
                    run += v;
                }
                if (curg >= 0) atomicAdd(&psum[curg * 384 + col], run);
            }
        }
    }
}

// node-parallel feature pooling: block covers 128 nodes; thread = (col, half);
// 64 serial rows per thread with run-accumulation by graph id + boundary atomics
__global__ void k_poolnodes(const unsigned short* featb, const int* batch32, float* psum) {
    int col = threadIdx.x & 127;
    int half = threadIdx.x >> 7;
    int nbeg = blockIdx.x * 128 + half * 64;
    if (nbeg >= NNODES) return;
    int nend = nbeg + 64;
    if (nend > NNODES) nend = NNODES;
    float run = 0.f;
    int curg = batch32[nbeg];
    for (int n = nbeg; n < nend; ++n) {
        int g = batch32[n];
        if (g != curg) {
            atomicAdd(&psum[curg * 384 + 256 + col], run);
            run = 0.f;
            curg = g;
        }
        run += us2f(featb[(size_t)n * 128 + col]);
    }
    atomicAdd(&psum[curg * 384 + 256 + col], run);
}

__global__ void k_fc1(const float* psum, const int* pcnt, const float* w,
                      const float* b, float* h) {
    int g = blockIdx.x, j = threadIdx.x * 2;
    int c = pcnt[g];
    float inv = 1.f / (float)(c > 0 ? c : 1);
    float a0 = 0.f, a1 = 0.f;
    for (int k = 0; k < 384; ++k) {
        float p = psum[g * 384 + k];
        a0 += p * w[k * 512 + j];
        a1 += p * w[k * 512 + j + 1];
    }
    a0 = a0 * inv + b[j];
    a1 = a1 * inv + b[j + 1];
    h[g * 512 + j] = a0 > 0.f ? a0 : 0.f;
    h[g * 512 + j + 1] = a1 > 0.f ? a1 : 0.f;
}

// final FC2 + store — carries the harness identifier name on purpose.
__global__ void ChebModel_74380243632480_kernel(const float* h, const float* w,
                                                const float* b, const int* fflag,
                                                void* out) {
    int g = blockIdx.x, j = threadIdx.x;
    float acc = 0.f;
    for (int k = 0; k < 512; ++k) acc += h[g * 512 + k] * w[k * 128 + j];
    acc += b[j];
    if (*fflag) ((unsigned short*)out)[g * 128 + j] = f2us(acc);
    else ((float*)out)[g * 128 + j] = acc;
}

extern "C" void kernel_launch(void* const* d_in, const int* in_sizes, int n_in,
                              void* d_out, int out_size, void* d_ws, size_t ws_size,
                              hipStream_t stream) {
    const void* feature = d_in[0];
    const int* edge_index = (const int*)d_in[1];
    const int* batch = (const int*)d_in[2];
    const void* W1 = d_in[3];
    const void* b1 = d_in[4];
    const void* W2 = d_in[5];
    const void* b2 = d_in[6];
    const void* fc1w = d_in[7];
    const void* fc1b = d_in[8];
    const void* fc2w = d_in[9];
    const void* fc2b = d_in[10];

    char* ws = (char*)d_ws;
    size_t off = 0;
    int* iflag = (int*)(ws + off); off += 256;
    int* fflag = (int*)(ws + off); off += 256;
    int* deg = (int*)(ws + off); off += ((size_t)NNODES * 4 + 255) & ~(size_t)255;
    int* indeg = (int*)(ws + off); off += ((size_t)NNODES * 4 + 255) & ~(size_t)255;
    int* cursor = (int*)(ws + off); off += ((size_t)NNODES * 4 + 255) & ~(size_t)255;
    int* rowptr = (int*)(ws + off); off += ((size_t)(NNODES + 1) * 4 + 255) & ~(size_t)255;
    float* dinv = (float*)(ws + off); off += ((size_t)NNODES * 4 + 255) & ~(size_t)255;
    int* batch32 = (int*)(ws + off); off += ((size_t)NNODES * 4 + 255) & ~(size_t)255;
    int* bsum = (int*)(ws + off); off += 1024;
    int* boff = (int*)(ws + off); off += 1024;
    int* csr_src = (int*)(ws + off); off += ((size_t)NEDGES * 4 + 255) & ~(size_t)255;
    float* csr_w = (float*)(ws + off); off += ((size_t)NEDGES * 4 + 255) & ~(size_t)255;
    unsigned short* featb = (unsigned short*)(ws + off); off += ((size_t)NNODES * 128 * 2 + 255) & ~(size_t)255;
    unsigned short* T1 = (unsigned short*)(ws + off); off += ((size_t)NNODES * 128 * 2 + 255) & ~(size_t)255;
    unsigned short* T2 = (unsigned short*)(ws + off); off += ((size_t)NNODES * 128 * 2 + 255) & ~(size_t)255;
    unsigned short* gx1 = (unsigned short*)(ws + off); off += ((size_t)NNODES * 128 * 2 + 255) & ~(size_t)255;
    unsigned short* W1t = (unsigned short*)(ws + off); off += ((size_t)49152 * 2 + 255) & ~(size_t)255;
    unsigned short* W2t = (unsigned short*)(ws + off); off += ((size_t)98304 * 2 + 255) & ~(size_t)255;
    float* b1f = (float*)(ws + off); off += 1024;
    float* b2f = (float*)(ws + off); off += 1024;
    float* fc1wf = (float*)(ws + off); off += ((size_t)196608 * 4 + 255) & ~(size_t)255;
    float* fc1bf = (float*)(ws + off); off += 2048;
    float* fc2wf = (float*)(ws + off); off += ((size_t)65536 * 4 + 255) & ~(size_t)255;
    float* fc2bf = (float*)(ws + off); off += 1024;
    float* psum = (float*)(ws + off); off += ((size_t)128 * 384 * 4 + 255) & ~(size_t)255;
    int* pcnt = (int*)(ws + off); off += 1024;
    float* hbuf = (float*)(ws + off); off += ((size_t)128 * 512 * 4 + 255) & ~(size_t)255;

    k_detect<<<1, 64, 0, stream>>>(edge_index, (const unsigned int*)feature, iflag, fflag);
    k_init<<<(NNODES + 255) / 256, 256, 0, stream>>>(batch, iflag, deg, indeg, batch32, psum);
    k_degree<<<(NEDGES + 255) / 256, 256, 0, stream>>>(edge_index, iflag, deg, indeg);
    k_scan1<<<NB, 256, 0, stream>>>(indeg, deg, bsum, dinv);
    k_scan2<<<1, 256, 0, stream>>>(bsum, boff, rowptr, batch32, pcnt);
    k_scan3<<<NB, 256, 0, stream>>>(indeg, boff, rowptr, cursor);
    k_fill<<<(NEDGES + 255) / 256, 256, 0, stream>>>(edge_index, iflag, dinv, cursor, csr_src, csr_w);

    k_featb<<<(NNODES * 128 / 8 + 255) / 256, 256, 0, stream>>>(feature, fflag, featb);
    k_trans2<<<(49152 + 98304 + 255) / 256, 256, 0, stream>>>(W1, W2, fflag, W1t, W2t);
    k_prepw<<<(263168 + 255) / 256, 256, 0, stream>>>(b1, b2, fc1w, fc1b, fc2w, fc2b, fflag,
                                                      b1f, b2f, fc1wf, fc1bf, fc2wf, fc2bf);

    int pb = (NNODES * 64 + 255) / 256;
    size_t shbytes = 64 * 392 * 2;  // 50176 B
    // conv1: T1 = prop(featb), T2 = 2*prop(T1) - featb, gx1 = relu([f|T1|T2]@W1 + b1)
    k_prop<<<pb, 256, 0, stream>>>(featb, rowptr, csr_src, csr_w, (const unsigned short*)0, 1.f, 0.f, T1);
    k_prop<<<pb, 256, 0, stream>>>(T1, rowptr, csr_src, csr_w, featb, 2.f, -1.f, T2);
    {
        dim3 g1((NNODES + 255) / 256, 2);
        k_convg<<<g1, 512, shbytes, stream>>>(featb, T1, T2, W1t, b1f, gx1,
                                              (const int*)0, (float*)0, 128, 0);
    }
    // conv2 with fused mean-pool epilogue
    k_prop<<<pb, 256, 0, stream>>>(gx1, rowptr, csr_src, csr_w, (const unsigned short*)0, 1.f, 0.f, T1);
    k_prop<<<pb, 256, 0, stream>>>(T1, rowptr, csr_src, csr_w, gx1, 2.f, -1.f, T2);
    {
        dim3 g2((NNODES + 255) / 256, 4);
        k_convg<<<g2, 512, shbytes, stream>>>(gx1, T1, T2, W2t, b2f, (unsigned short*)0,
                                              batch32, psum, 256, 1);
    }
    // feature part of pooling (node-parallel), then FC head
    k_poolnodes<<<(NNODES + 127) / 128, 256, 0, stream>>>(featb, batch32, psum);
    k_fc1<<<128, 256, 0, stream>>>(psum, pcnt, fc1wf, fc1bf, hbuf);
    ChebModel_74380243632480_kernel<<<128, 128, 0, stream>>>(hbuf, fc2wf, fc2bf, fflag, d_out);
}